// Round 1
// baseline (390.875 us; speedup 1.0000x reference)
//
#include <hip/hip_runtime.h>
#include <math.h>

// Fused AdderNet bottleneck block for MI355X.
// Pipeline (all fp32):
//   recon+KL (4 weight tensors) -> adder_ds(1x1,128->256) -> bnds stats
//   adder_c1(1x1,128->64) -> PEG depthwise 3x3 -> bn1 stats -> bn1 apply(relu)
//   adder_c2(3x3,64->64) -> bn2 stats -> bn2 apply(relu)
//   adder_c3(1x1,64->256) -> bn3 stats -> final: relu(bn3(h)+relu(bnds(t_ds))), kl sum
//
// All kernels use blockDim=256 (4 waves of 64).

#define HW 784      // 28*28
#define NB 4        // batch
#define STAGE 100

// ---------------- block reduction helpers (blockDim must be 256) -----------
__device__ __forceinline__ float wredSum(float v){
  for (int o = 32; o > 0; o >>= 1) v += __shfl_down(v, o, 64);
  return v;
}
__device__ __forceinline__ float wredMax(float v){
  for (int o = 32; o > 0; o >>= 1) v = fmaxf(v, __shfl_down(v, o, 64));
  return v;
}
__device__ __forceinline__ float wredMin(float v){
  for (int o = 32; o > 0; o >>= 1) v = fminf(v, __shfl_down(v, o, 64));
  return v;
}

__device__ float blockSum(float v){
  __shared__ float sh[4];
  __syncthreads();                 // protect sh from previous call's readers
  v = wredSum(v);
  if ((threadIdx.x & 63) == 0) sh[threadIdx.x >> 6] = v;
  __syncthreads();
  return sh[0] + sh[1] + sh[2] + sh[3];
}
__device__ float blockMax(float v){
  __shared__ float sh[4];
  __syncthreads();
  v = wredMax(v);
  if ((threadIdx.x & 63) == 0) sh[threadIdx.x >> 6] = v;
  __syncthreads();
  return fmaxf(fmaxf(sh[0], sh[1]), fmaxf(sh[2], sh[3]));
}
__device__ float blockMin(float v){
  __shared__ float sh[4];
  __syncthreads();
  v = wredMin(v);
  if ((threadIdx.x & 63) == 0) sh[threadIdx.x >> 6] = v;
  __syncthreads();
  return fminf(fminf(sh[0], sh[1]), fminf(sh[2], sh[3]));
}

// --------------- weight reconstruction (binning) + KL vs Laplace -----------
// One block per weight tensor (grid = 4).
__global__ __launch_bounds__(256) void recon_kl_kernel(
    const float* w0, const float* a0, const float* l0, float* f0, int n0,
    const float* w1, const float* a1, const float* l1, float* f1, int n1,
    const float* w2, const float* a2, const float* l2, float* f2, int n2,
    const float* w3, const float* a3, const float* l3, float* f3, int n3,
    float* kl_out)
{
  const float* w; const float* aff; const float* lap; float* f; int n;
  int t = blockIdx.x;
  if      (t == 0){ w = w0; aff = a0; lap = l0; f = f0; n = n0; }
  else if (t == 1){ w = w1; aff = a1; lap = l1; f = f1; n = n1; }
  else if (t == 2){ w = w2; aff = a2; lap = l2; f = f2; n = n2; }
  else            { w = w3; aff = a3; lap = l3; f = f3; n = n3; }

  __shared__ float saff[STAGE];
  for (int i = threadIdx.x; i < STAGE; i += 256) saff[i] = aff[i];
  __syncthreads();

  // pass 1: min/max of w
  float mn = 3.402823466e38f, mx = -3.402823466e38f;
  for (int i = threadIdx.x; i < n; i += 256){
    float v = w[i];
    mn = fminf(mn, v); mx = fmaxf(mx, v);
  }
  mn = blockMin(mn); mx = blockMax(mx);
  float rng = mx - mn;

  // pass 2: reconstruct, track max(new).  Mirror reference op order exactly:
  // idx = floor(((w-wmin)/(wmax-wmin)) * 100); mask = idx<100; scale=aff[clip]
  float maxnew = -3.402823466e38f;
  for (int i = threadIdx.x; i < n; i += 256){
    float v = w[i];
    float q = (v - mn) / rng * 100.0f;
    int idx = (int)floorf(q);
    float nv = 0.0f;
    if (idx < STAGE){
      int ci = idx < 0 ? 0 : (idx > STAGE - 1 ? STAGE - 1 : idx);
      nv = v * saff[ci];
    }
    f[i] = nv;
    maxnew = fmaxf(maxnew, nv);
  }
  maxnew = blockMax(maxnew);

  // pass 3: sum exp(new - maxnew)
  float s = 0.0f;
  for (int i = threadIdx.x; i < n; i += 256) s += expf(f[i] - maxnew);
  float Snew = blockSum(s);

  // pass 4: max(lap)
  float maxl = -3.402823466e38f;
  for (int i = threadIdx.x; i < n; i += 256) maxl = fmaxf(maxl, lap[i]);
  maxl = blockMax(maxl);

  // pass 5: sum exp(lap - maxl)
  s = 0.0f;
  for (int i = threadIdx.x; i < n; i += 256) s += expf(lap[i] - maxl);
  float Slap = blockSum(s);

  // pass 6: sum p*(logp - logq)
  float logSl = logf(Slap), logSn = logf(Snew);
  float invSlap = 1.0f / Slap;
  float acc = 0.0f;
  for (int i = threadIdx.x; i < n; i += 256){
    float ls = lap[i] - maxl;
    float p  = expf(ls) * invSlap;
    float lp = ls - logSl;
    float lq = f[i] - maxnew - logSn;
    acc += p * (lp - lq);
  }
  acc = blockSum(acc);
  if (threadIdx.x == 0) kl_out[t] = acc / (float)n;
}

// --------------------- 1x1 adder "conv" ------------------------------------
// X: (4, CI, 28, 28)  W: (O, CI)  out: (4, O, 28, 28)
// out[b,o,hw] = -sum_c |X[b,c,hw] - W[o,c]|
// Block of 256 consecutive outputs spans at most 2 (b,o) rows -> stage both
// weight rows in LDS.
template<int CI, int O>
__global__ __launch_bounds__(256) void adder1x1_kernel(
    const float* __restrict__ X, const float* __restrict__ W,
    float* __restrict__ out)
{
  __shared__ float sw[2 * CI];
  const int n0 = blockIdx.x * 256;
  const int g_base = n0 / HW;              // g = b*O + o
  const int maxG = NB * O;
  for (int k = threadIdx.x; k < 2 * CI; k += 256){
    int row = k / CI;
    int gg = g_base + row;
    if (gg < maxG) sw[k] = W[(gg % O) * CI + (k - row * CI)];
  }
  __syncthreads();

  const int n = n0 + threadIdx.x;
  const int g = n / HW;
  const int hw = n - g * HW;
  const int b = g / O;
  const float* wr = sw + (g - g_base) * CI;
  const float* xp = X + (size_t)(b * CI) * HW + hw;
  float acc = 0.0f;
  #pragma unroll 8
  for (int c = 0; c < CI; c++)
    acc += fabsf(xp[(size_t)c * HW] - wr[c]);
  out[n] = -acc;
}

// --------------------- PEG depthwise 3x3 adder -----------------------------
// X: (4,64,28,28)  W: (64,9)  out: (4,64,28,28), zero padding contributes |0-w|
__global__ __launch_bounds__(256) void peg_kernel(
    const float* __restrict__ X, const float* __restrict__ W,
    float* __restrict__ out)
{
  __shared__ float sw[576];
  for (int k = threadIdx.x; k < 576; k += 256) sw[k] = W[k];
  __syncthreads();

  const int n = blockIdx.x * 256 + threadIdx.x;
  const int g = n / HW;          // b*64+o
  const int hw = n - g * HW;
  const int o = g & 63;
  const int y = hw / 28, x = hw - (hw / 28) * 28;
  const float* xp = X + (size_t)g * HW;
  const float* wr = sw + o * 9;
  float acc = 0.0f;
  #pragma unroll
  for (int ky = 0; ky < 3; ky++){
    int iy = y + ky - 1;
    bool vy = (iy >= 0) && (iy < 28);
    #pragma unroll
    for (int kx = 0; kx < 3; kx++){
      int ix = x + kx - 1;
      float v = (vy && ix >= 0 && ix < 28) ? xp[iy * 28 + ix] : 0.0f;
      acc += fabsf(v - wr[ky * 3 + kx]);
    }
  }
  out[n] = -acc;
}

// --------------------- 3x3 adder conv (64 -> 64, pad 1) --------------------
// X: (4,64,28,28)  W: (64, 576)  out: (4,64,28,28)
__global__ __launch_bounds__(256) void adder3x3_kernel(
    const float* __restrict__ X, const float* __restrict__ W,
    float* __restrict__ out)
{
  __shared__ float sw[2 * 576];
  const int n0 = blockIdx.x * 256;
  const int g_base = n0 / HW;
  for (int k = threadIdx.x; k < 1152; k += 256){
    int row = k / 576;
    int gg = g_base + row;
    if (gg < NB * 64) sw[k] = W[(gg & 63) * 576 + (k - row * 576)];
  }
  __syncthreads();

  const int n = n0 + threadIdx.x;
  const int g = n / HW;
  const int hw = n - g * HW;
  const int b = g >> 6;
  const int y = hw / 28, x = hw - (hw / 28) * 28;
  const float* wr = sw + (g - g_base) * 576;
  const float* xb = X + (size_t)b * 64 * HW;
  float acc = 0.0f;
  for (int c = 0; c < 64; c++){
    const float* xc = xb + (size_t)c * HW;
    const float* wc = wr + c * 9;
    #pragma unroll
    for (int ky = 0; ky < 3; ky++){
      int iy = y + ky - 1;
      bool vy = (iy >= 0) && (iy < 28);
      #pragma unroll
      for (int kx = 0; kx < 3; kx++){
        int ix = x + kx - 1;
        float v = (vy && ix >= 0 && ix < 28) ? xc[iy * 28 + ix] : 0.0f;
        acc += fabsf(v - wc[ky * 3 + kx]);
      }
    }
  }
  out[n] = -acc;
}

// --------------------- BN training-mode stats ------------------------------
// One block per channel; two-pass (mean, then biased var) for fp32 safety.
// stats[2c] = gamma*rsqrt(var+eps); stats[2c+1] = beta - mean*scale
__global__ __launch_bounds__(256) void bn_stats_kernel(
    const float* __restrict__ X, const float* __restrict__ gam,
    const float* __restrict__ bet, float* __restrict__ stats, int C)
{
  const int c = blockIdx.x;
  float s = 0.0f;
  for (int i = threadIdx.x; i < NB * HW; i += 256){
    int b = i / HW, hw = i - b * HW;
    s += X[(size_t)(b * C + c) * HW + hw];
  }
  s = blockSum(s);
  const float mean = s * (1.0f / (NB * HW));
  float sq = 0.0f;
  for (int i = threadIdx.x; i < NB * HW; i += 256){
    int b = i / HW, hw = i - b * HW;
    float d = X[(size_t)(b * C + c) * HW + hw] - mean;
    sq += d * d;
  }
  sq = blockSum(sq);
  if (threadIdx.x == 0){
    float var = sq * (1.0f / (NB * HW));
    float scale = gam[c] * rsqrtf(var + 1e-5f);
    stats[2 * c]     = scale;
    stats[2 * c + 1] = bet[c] - mean * scale;
  }
}

// --------------------- BN apply + relu (in place, C=64) --------------------
__global__ __launch_bounds__(256) void bn_apply_relu_kernel(
    float* __restrict__ X, const float* __restrict__ stats, int C)
{
  const int n = blockIdx.x * 256 + threadIdx.x;
  const int c = (n / HW) % C;
  float v = X[n] * stats[2 * c] + stats[2 * c + 1];
  X[n] = fmaxf(v, 0.0f);
}

// --------------------- final: relu(bn3(h) + relu(bnds(t_ds))) + kl ---------
__global__ __launch_bounds__(256) void final_kernel(
    float* __restrict__ outp, const float* __restrict__ A,
    const float* __restrict__ s3, const float* __restrict__ sds,
    const float* __restrict__ kl)
{
  const int n = blockIdx.x * 256 + threadIdx.x;
  const int c = (n / HW) & 255;
  float v3  = outp[n] * s3[2 * c] + s3[2 * c + 1];
  float res = fmaxf(A[n] * sds[2 * c] + sds[2 * c + 1], 0.0f);
  outp[n] = fmaxf(v3 + res, 0.0f);
  if (n == 0) outp[802816] = kl[0] + kl[1] + kl[2] + kl[3];
}

// ===========================================================================
extern "C" void kernel_launch(void* const* d_in, const int* in_sizes, int n_in,
                              void* d_out, int out_size, void* d_ws, size_t ws_size,
                              hipStream_t stream)
{
  const float* x      = (const float*)d_in[0];
  const float* sw_ds  = (const float*)d_in[1];
  const float* sw_c1  = (const float*)d_in[2];
  const float* sw_c2  = (const float*)d_in[3];
  const float* sw_c3  = (const float*)d_in[4];
  const float* a_ds   = (const float*)d_in[5];
  const float* a_c1   = (const float*)d_in[6];
  const float* a_c2   = (const float*)d_in[7];
  const float* a_c3   = (const float*)d_in[8];
  const float* peg_w  = (const float*)d_in[9];
  const float* bn1_g  = (const float*)d_in[10];
  const float* bn1_b  = (const float*)d_in[11];
  const float* bn2_g  = (const float*)d_in[12];
  const float* bn2_b  = (const float*)d_in[13];
  const float* bn3_g  = (const float*)d_in[14];
  const float* bn3_b  = (const float*)d_in[15];
  const float* bnds_g = (const float*)d_in[16];
  const float* bnds_b = (const float*)d_in[17];
  const float* lap_ds = (const float*)d_in[18];
  const float* lap_c1 = (const float*)d_in[19];
  const float* lap_c2 = (const float*)d_in[20];
  const float* lap_c3 = (const float*)d_in[21];

  float* ws   = (float*)d_ws;
  float* f_ds = ws;                 // 32768
  float* f_c1 = ws + 32768;         // 8192
  float* f_c2 = ws + 40960;         // 36864
  float* f_c3 = ws + 77824;         // 16384
  float* kl   = ws + 94208;         // 4
  float* sds  = ws + 94212;         // 512
  float* s1   = ws + 94724;         // 128
  float* s2   = ws + 94852;         // 128
  float* s3   = ws + 94980;         // 512
  float* A    = ws + 95492;         // 802816  (t_ds, pre-BN)
  float* T1   = A  + 802816;        // 200704
  float* T2   = T1 + 200704;        // 200704
  float* T3   = T2 + 200704;        // 200704  (total ~6.0 MB)

  float* out = (float*)d_out;

  // 1) weight reconstruction + KL terms
  recon_kl_kernel<<<4, 256, 0, stream>>>(
      sw_ds, a_ds, lap_ds, f_ds, 32768,
      sw_c1, a_c1, lap_c1, f_c1, 8192,
      sw_c2, a_c2, lap_c2, f_c2, 36864,
      sw_c3, a_c3, lap_c3, f_c3, 16384, kl);

  // 2) downsample branch: adder 1x1 (128->256), stats deferred to final
  adder1x1_kernel<128, 256><<<3136, 256, 0, stream>>>(x, f_ds, A);
  bn_stats_kernel<<<256, 256, 0, stream>>>(A, bnds_g, bnds_b, sds, 256);

  // 3) main branch
  adder1x1_kernel<128, 64><<<784, 256, 0, stream>>>(x, f_c1, T1);
  peg_kernel<<<784, 256, 0, stream>>>(T1, peg_w, T2);
  bn_stats_kernel<<<64, 256, 0, stream>>>(T2, bn1_g, bn1_b, s1, 64);
  bn_apply_relu_kernel<<<784, 256, 0, stream>>>(T2, s1, 64);

  adder3x3_kernel<<<784, 256, 0, stream>>>(T2, f_c2, T3);
  bn_stats_kernel<<<64, 256, 0, stream>>>(T3, bn2_g, bn2_b, s2, 64);
  bn_apply_relu_kernel<<<784, 256, 0, stream>>>(T3, s2, 64);

  adder1x1_kernel<64, 256><<<3136, 256, 0, stream>>>(T3, f_c3, out);
  bn_stats_kernel<<<256, 256, 0, stream>>>(out, bn3_g, bn3_b, s3, 256);

  // 4) epilogue: bn3 + residual(bnds+relu) + relu, plus kl scalar
  final_kernel<<<3136, 256, 0, stream>>>(out, A, s3, sds, kl);
}

// Round 2
// 231.172 us; speedup vs baseline: 1.6908x; 1.6908x over previous
//
#include <hip/hip_runtime.h>
#include <math.h>

// Fused AdderNet bottleneck block for MI355X.
// R2: recon_kl rewritten — 3 vectorized passes (float4), 1024 thr/block,
//     aggregated-KL identity removes 3 of 6 passes. R1 profile showed it
//     was 200/390 us at 0.12% occupancy.

#define HW 784      // 28*28
#define NB 4        // batch
#define STAGE 100

// ---------------- wave/block reduction helpers -----------------------------
__device__ __forceinline__ float wredSum(float v){
  for (int o = 32; o > 0; o >>= 1) v += __shfl_down(v, o, 64);
  return v;
}
__device__ __forceinline__ float wredMax(float v){
  for (int o = 32; o > 0; o >>= 1) v = fmaxf(v, __shfl_down(v, o, 64));
  return v;
}
__device__ __forceinline__ float wredMin(float v){
  for (int o = 32; o > 0; o >>= 1) v = fminf(v, __shfl_down(v, o, 64));
  return v;
}

// blockDim = 256 variants (4 waves) — used by bn_stats
__device__ float blockSum(float v){
  __shared__ float sh[4];
  __syncthreads();
  v = wredSum(v);
  if ((threadIdx.x & 63) == 0) sh[threadIdx.x >> 6] = v;
  __syncthreads();
  return sh[0] + sh[1] + sh[2] + sh[3];
}

// blockDim = 1024 variants (16 waves) — used by recon_kl
__device__ float blockSum16(float v){
  __shared__ float sh[16];
  __syncthreads();
  v = wredSum(v);
  if ((threadIdx.x & 63) == 0) sh[threadIdx.x >> 6] = v;
  __syncthreads();
  float r = 0.0f;
  #pragma unroll
  for (int i = 0; i < 16; i++) r += sh[i];
  return r;
}
__device__ float blockMax16(float v){
  __shared__ float sh[16];
  __syncthreads();
  v = wredMax(v);
  if ((threadIdx.x & 63) == 0) sh[threadIdx.x >> 6] = v;
  __syncthreads();
  float r = sh[0];
  #pragma unroll
  for (int i = 1; i < 16; i++) r = fmaxf(r, sh[i]);
  return r;
}
__device__ float blockMin16(float v){
  __shared__ float sh[16];
  __syncthreads();
  v = wredMin(v);
  if ((threadIdx.x & 63) == 0) sh[threadIdx.x >> 6] = v;
  __syncthreads();
  float r = sh[0];
  #pragma unroll
  for (int i = 1; i < 16; i++) r = fminf(r, sh[i]);
  return r;
}

// --------------- weight reconstruction (binning) + KL vs Laplace -----------
// One block (1024 thr) per weight tensor (grid = 4). 3 float4 passes:
//   P1: min/max(w), max(lap)
//   P2: f = recon(w), max(f)
//   P3: S=sum e, sum e*lap, sum e*f, Q=sum exp(f-maxf);  e=exp(lap-maxl)
// KL = [ (sum e*lap - sum e*f)/S - maxl - log S + maxf + log Q ] / n
__global__ __launch_bounds__(1024) void recon_kl_kernel(
    const float* w0, const float* a0, const float* l0, float* f0, int n0,
    const float* w1, const float* a1, const float* l1, float* f1, int n1,
    const float* w2, const float* a2, const float* l2, float* f2, int n2,
    const float* w3, const float* a3, const float* l3, float* f3, int n3,
    float* kl_out)
{
  const float* w; const float* aff; const float* lap; float* f; int n;
  int t = blockIdx.x;
  if      (t == 0){ w = w0; aff = a0; lap = l0; f = f0; n = n0; }
  else if (t == 1){ w = w1; aff = a1; lap = l1; f = f1; n = n1; }
  else if (t == 2){ w = w2; aff = a2; lap = l2; f = f2; n = n2; }
  else            { w = w3; aff = a3; lap = l3; f = f3; n = n3; }

  __shared__ float saff[STAGE];
  for (int i = threadIdx.x; i < STAGE; i += 1024) saff[i] = aff[i];

  const float4* w4 = (const float4*)w;
  const float4* l4 = (const float4*)lap;
  float4*       f4 = (float4*)f;
  const int n4 = n >> 2;

  // ---- pass 1: min/max of w, max of lap ----
  float mn = 3.402823466e38f, mx = -3.402823466e38f, ml = -3.402823466e38f;
  for (int i = threadIdx.x; i < n4; i += 1024){
    float4 v = w4[i];
    mn = fminf(mn, fminf(fminf(v.x, v.y), fminf(v.z, v.w)));
    mx = fmaxf(mx, fmaxf(fmaxf(v.x, v.y), fmaxf(v.z, v.w)));
    float4 u = l4[i];
    ml = fmaxf(ml, fmaxf(fmaxf(u.x, u.y), fmaxf(u.z, u.w)));
  }
  mn = blockMin16(mn); mx = blockMax16(mx); ml = blockMax16(ml);
  const float rng = mx - mn;

  // ---- pass 2: reconstruct, track max(f) ----
  // Mirror reference op order: idx = floor((w-wmin)/(wmax-wmin)*100);
  // mask = idx<100; scale = aff[clip(idx,0,99)]
  float maxf = -3.402823466e38f;
  for (int i = threadIdx.x; i < n4; i += 1024){
    float4 v = w4[i];
    float4 o;
    float* vp = &v.x; float* op = &o.x;
    #pragma unroll
    for (int k = 0; k < 4; k++){
      float vv = vp[k];
      float q = (vv - mn) / rng * 100.0f;
      int idx = (int)floorf(q);
      float nv = 0.0f;
      if (idx < STAGE){
        int ci = idx < 0 ? 0 : (idx > STAGE - 1 ? STAGE - 1 : idx);
        nv = vv * saff[ci];
      }
      op[k] = nv;
      maxf = fmaxf(maxf, nv);
    }
    f4[i] = o;
  }
  maxf = blockMax16(maxf);

  // ---- pass 3: weighted sums ----
  float se = 0.0f, sel = 0.0f, sef = 0.0f, sq = 0.0f;
  for (int i = threadIdx.x; i < n4; i += 1024){
    float4 u = l4[i];
    float4 fv = f4[i];
    float* up = &u.x; float* fp = &fv.x;
    #pragma unroll
    for (int k = 0; k < 4; k++){
      float e = expf(up[k] - ml);
      se  += e;
      sel += e * up[k];
      sef += e * fp[k];
      sq  += expf(fp[k] - maxf);
    }
  }
  se  = blockSum16(se);
  sel = blockSum16(sel);
  sef = blockSum16(sef);
  sq  = blockSum16(sq);

  if (threadIdx.x == 0){
    float kl = ((sel - sef) / se - ml - logf(se) + maxf + logf(sq)) / (float)n;
    kl_out[t] = kl;
  }
}

// --------------------- 1x1 adder "conv" ------------------------------------
// X: (4, CI, 28, 28)  W: (O, CI)  out: (4, O, 28, 28)
// out[b,o,hw] = -sum_c |X[b,c,hw] - W[o,c]|
template<int CI, int O>
__global__ __launch_bounds__(256) void adder1x1_kernel(
    const float* __restrict__ X, const float* __restrict__ W,
    float* __restrict__ out)
{
  __shared__ float sw[2 * CI];
  const int n0 = blockIdx.x * 256;
  const int g_base = n0 / HW;              // g = b*O + o
  const int maxG = NB * O;
  for (int k = threadIdx.x; k < 2 * CI; k += 256){
    int row = k / CI;
    int gg = g_base + row;
    if (gg < maxG) sw[k] = W[(gg % O) * CI + (k - row * CI)];
  }
  __syncthreads();

  const int n = n0 + threadIdx.x;
  const int g = n / HW;
  const int hw = n - g * HW;
  const int b = g / O;
  const float* wr = sw + (g - g_base) * CI;
  const float* xp = X + (size_t)(b * CI) * HW + hw;
  float acc = 0.0f;
  #pragma unroll 8
  for (int c = 0; c < CI; c++)
    acc += fabsf(xp[(size_t)c * HW] - wr[c]);
  out[n] = -acc;
}

// --------------------- PEG depthwise 3x3 adder -----------------------------
__global__ __launch_bounds__(256) void peg_kernel(
    const float* __restrict__ X, const float* __restrict__ W,
    float* __restrict__ out)
{
  __shared__ float sw[576];
  for (int k = threadIdx.x; k < 576; k += 256) sw[k] = W[k];
  __syncthreads();

  const int n = blockIdx.x * 256 + threadIdx.x;
  const int g = n / HW;          // b*64+o
  const int hw = n - g * HW;
  const int o = g & 63;
  const int y = hw / 28, x = hw - (hw / 28) * 28;
  const float* xp = X + (size_t)g * HW;
  const float* wr = sw + o * 9;
  float acc = 0.0f;
  #pragma unroll
  for (int ky = 0; ky < 3; ky++){
    int iy = y + ky - 1;
    bool vy = (iy >= 0) && (iy < 28);
    #pragma unroll
    for (int kx = 0; kx < 3; kx++){
      int ix = x + kx - 1;
      float v = (vy && ix >= 0 && ix < 28) ? xp[iy * 28 + ix] : 0.0f;
      acc += fabsf(v - wr[ky * 3 + kx]);
    }
  }
  out[n] = -acc;
}

// --------------------- 3x3 adder conv (64 -> 64, pad 1) --------------------
__global__ __launch_bounds__(256) void adder3x3_kernel(
    const float* __restrict__ X, const float* __restrict__ W,
    float* __restrict__ out)
{
  __shared__ float sw[2 * 576];
  const int n0 = blockIdx.x * 256;
  const int g_base = n0 / HW;
  for (int k = threadIdx.x; k < 1152; k += 256){
    int row = k / 576;
    int gg = g_base + row;
    if (gg < NB * 64) sw[k] = W[(gg & 63) * 576 + (k - row * 576)];
  }
  __syncthreads();

  const int n = n0 + threadIdx.x;
  const int g = n / HW;
  const int hw = n - g * HW;
  const int b = g >> 6;
  const int y = hw / 28, x = hw - (hw / 28) * 28;
  const float* wr = sw + (g - g_base) * 576;
  const float* xb = X + (size_t)b * 64 * HW;
  float acc = 0.0f;
  for (int c = 0; c < 64; c++){
    const float* xc = xb + (size_t)c * HW;
    const float* wc = wr + c * 9;
    #pragma unroll
    for (int ky = 0; ky < 3; ky++){
      int iy = y + ky - 1;
      bool vy = (iy >= 0) && (iy < 28);
      #pragma unroll
      for (int kx = 0; kx < 3; kx++){
        int ix = x + kx - 1;
        float v = (vy && ix >= 0 && ix < 28) ? xc[iy * 28 + ix] : 0.0f;
        acc += fabsf(v - wc[ky * 3 + kx]);
      }
    }
  }
  out[n] = -acc;
}

// --------------------- BN training-mode stats ------------------------------
__global__ __launch_bounds__(256) void bn_stats_kernel(
    const float* __restrict__ X, const float* __restrict__ gam,
    const float* __restrict__ bet, float* __restrict__ stats, int C)
{
  const int c = blockIdx.x;
  float s = 0.0f;
  for (int i = threadIdx.x; i < NB * HW; i += 256){
    int b = i / HW, hw = i - b * HW;
    s += X[(size_t)(b * C + c) * HW + hw];
  }
  s = blockSum(s);
  const float mean = s * (1.0f / (NB * HW));
  float sq = 0.0f;
  for (int i = threadIdx.x; i < NB * HW; i += 256){
    int b = i / HW, hw = i - b * HW;
    float d = X[(size_t)(b * C + c) * HW + hw] - mean;
    sq += d * d;
  }
  sq = blockSum(sq);
  if (threadIdx.x == 0){
    float var = sq * (1.0f / (NB * HW));
    float scale = gam[c] * rsqrtf(var + 1e-5f);
    stats[2 * c]     = scale;
    stats[2 * c + 1] = bet[c] - mean * scale;
  }
}

// --------------------- BN apply + relu (in place) --------------------------
__global__ __launch_bounds__(256) void bn_apply_relu_kernel(
    float* __restrict__ X, const float* __restrict__ stats, int C)
{
  const int n = blockIdx.x * 256 + threadIdx.x;
  const int c = (n / HW) % C;
  float v = X[n] * stats[2 * c] + stats[2 * c + 1];
  X[n] = fmaxf(v, 0.0f);
}

// --------------------- final: relu(bn3(h) + relu(bnds(t_ds))) + kl ---------
__global__ __launch_bounds__(256) void final_kernel(
    float* __restrict__ outp, const float* __restrict__ A,
    const float* __restrict__ s3, const float* __restrict__ sds,
    const float* __restrict__ kl)
{
  const int n = blockIdx.x * 256 + threadIdx.x;
  const int c = (n / HW) & 255;
  float v3  = outp[n] * s3[2 * c] + s3[2 * c + 1];
  float res = fmaxf(A[n] * sds[2 * c] + sds[2 * c + 1], 0.0f);
  outp[n] = fmaxf(v3 + res, 0.0f);
  if (n == 0) outp[802816] = kl[0] + kl[1] + kl[2] + kl[3];
}

// ===========================================================================
extern "C" void kernel_launch(void* const* d_in, const int* in_sizes, int n_in,
                              void* d_out, int out_size, void* d_ws, size_t ws_size,
                              hipStream_t stream)
{
  const float* x      = (const float*)d_in[0];
  const float* sw_ds  = (const float*)d_in[1];
  const float* sw_c1  = (const float*)d_in[2];
  const float* sw_c2  = (const float*)d_in[3];
  const float* sw_c3  = (const float*)d_in[4];
  const float* a_ds   = (const float*)d_in[5];
  const float* a_c1   = (const float*)d_in[6];
  const float* a_c2   = (const float*)d_in[7];
  const float* a_c3   = (const float*)d_in[8];
  const float* peg_w  = (const float*)d_in[9];
  const float* bn1_g  = (const float*)d_in[10];
  const float* bn1_b  = (const float*)d_in[11];
  const float* bn2_g  = (const float*)d_in[12];
  const float* bn2_b  = (const float*)d_in[13];
  const float* bn3_g  = (const float*)d_in[14];
  const float* bn3_b  = (const float*)d_in[15];
  const float* bnds_g = (const float*)d_in[16];
  const float* bnds_b = (const float*)d_in[17];
  const float* lap_ds = (const float*)d_in[18];
  const float* lap_c1 = (const float*)d_in[19];
  const float* lap_c2 = (const float*)d_in[20];
  const float* lap_c3 = (const float*)d_in[21];

  float* ws   = (float*)d_ws;
  float* f_ds = ws;                 // 32768
  float* f_c1 = ws + 32768;         // 8192
  float* f_c2 = ws + 40960;         // 36864
  float* f_c3 = ws + 77824;         // 16384
  float* kl   = ws + 94208;         // 4
  float* sds  = ws + 94212;         // 512
  float* s1   = ws + 94724;         // 128
  float* s2   = ws + 94852;         // 128
  float* s3   = ws + 94980;         // 512
  float* A    = ws + 95492;         // 802816  (t_ds, pre-BN)
  float* T1   = A  + 802816;        // 200704
  float* T2   = T1 + 200704;        // 200704
  float* T3   = T2 + 200704;        // 200704

  float* out = (float*)d_out;

  // 1) weight reconstruction + KL terms
  recon_kl_kernel<<<4, 1024, 0, stream>>>(
      sw_ds, a_ds, lap_ds, f_ds, 32768,
      sw_c1, a_c1, lap_c1, f_c1, 8192,
      sw_c2, a_c2, lap_c2, f_c2, 36864,
      sw_c3, a_c3, lap_c3, f_c3, 16384, kl);

  // 2) downsample branch: adder 1x1 (128->256)
  adder1x1_kernel<128, 256><<<3136, 256, 0, stream>>>(x, f_ds, A);
  bn_stats_kernel<<<256, 256, 0, stream>>>(A, bnds_g, bnds_b, sds, 256);

  // 3) main branch
  adder1x1_kernel<128, 64><<<784, 256, 0, stream>>>(x, f_c1, T1);
  peg_kernel<<<784, 256, 0, stream>>>(T1, peg_w, T2);
  bn_stats_kernel<<<64, 256, 0, stream>>>(T2, bn1_g, bn1_b, s1, 64);
  bn_apply_relu_kernel<<<784, 256, 0, stream>>>(T2, s1, 64);

  adder3x3_kernel<<<784, 256, 0, stream>>>(T2, f_c2, T3);
  bn_stats_kernel<<<64, 256, 0, stream>>>(T3, bn2_g, bn2_b, s2, 64);
  bn_apply_relu_kernel<<<784, 256, 0, stream>>>(T3, s2, 64);

  adder1x1_kernel<64, 256><<<3136, 256, 0, stream>>>(T3, f_c3, out);
  bn_stats_kernel<<<256, 256, 0, stream>>>(out, bn3_g, bn3_b, s3, 256);

  // 4) epilogue
  final_kernel<<<3136, 256, 0, stream>>>(out, A, s3, sds, kl);
}

// Round 3
// 204.461 us; speedup vs baseline: 1.9117x; 1.1306x over previous
//
#include <hip/hip_runtime.h>
#include <math.h>

// R3: 13 kernels -> 5. BN stats via block-reduced double atomics computed by
// producers; BN finalize+apply fused into consumers' load paths. PEG fused
// onto adder_c1 with LDS halo tile. 4-oc (2-oc for 3x3) output batching cuts
// L2 read traffic ~4x.

#define HW 784      // 28*28
#define NB 4
#define STAGE 100

// ---------------- wave reduction helpers (wave64) --------------------------
__device__ __forceinline__ float wredSum(float v){
  for (int o = 32; o > 0; o >>= 1) v += __shfl_down(v, o, 64);
  return v;
}
__device__ __forceinline__ float wredMax(float v){
  for (int o = 32; o > 0; o >>= 1) v = fmaxf(v, __shfl_down(v, o, 64));
  return v;
}
__device__ __forceinline__ float wredMin(float v){
  for (int o = 32; o > 0; o >>= 1) v = fminf(v, __shfl_down(v, o, 64));
  return v;
}
__device__ __forceinline__ double wredSumD(double v){
  for (int o = 32; o > 0; o >>= 1) v += __shfl_down(v, o, 64);
  return v;
}

// blockDim=1024 reductions (recon_kl)
__device__ float blockSum16(float v){
  __shared__ float sh[16];
  __syncthreads();
  v = wredSum(v);
  if ((threadIdx.x & 63) == 0) sh[threadIdx.x >> 6] = v;
  __syncthreads();
  float r = 0.0f;
  #pragma unroll
  for (int i = 0; i < 16; i++) r += sh[i];
  return r;
}
__device__ float blockMax16(float v){
  __shared__ float sh[16];
  __syncthreads();
  v = wredMax(v);
  if ((threadIdx.x & 63) == 0) sh[threadIdx.x >> 6] = v;
  __syncthreads();
  float r = sh[0];
  #pragma unroll
  for (int i = 1; i < 16; i++) r = fmaxf(r, sh[i]);
  return r;
}
__device__ float blockMin16(float v){
  __shared__ float sh[16];
  __syncthreads();
  v = wredMin(v);
  if ((threadIdx.x & 63) == 0) sh[threadIdx.x >> 6] = v;
  __syncthreads();
  float r = sh[0];
  #pragma unroll
  for (int i = 1; i < 16; i++) r = fminf(r, sh[i]);
  return r;
}

// ---- per-block stats accumulation: 4 channels, sum + sumsq, double atomics
// blockDim must be 256 (4 waves). All 256 threads must call (v* = 0 if idle).
__device__ void stats4(float v0, float v1, float v2, float v3,
                       double* sumP, double* sqP, int oc0){
  __shared__ double sred[4][8];
  const int w = threadIdx.x >> 6;
  float vv[4] = {v0, v1, v2, v3};
  #pragma unroll
  for (int i = 0; i < 4; i++){
    double d = (double)vv[i];
    double s = wredSumD(d);
    double q = wredSumD(d * d);
    if ((threadIdx.x & 63) == 0){ sred[w][i] = s; sred[w][4 + i] = q; }
  }
  __syncthreads();
  if (threadIdx.x < 8){
    double tot = sred[0][threadIdx.x] + sred[1][threadIdx.x]
               + sred[2][threadIdx.x] + sred[3][threadIdx.x];
    int i = threadIdx.x & 3;
    if (threadIdx.x < 4) atomicAdd(&sumP[oc0 + i], tot);
    else                 atomicAdd(&sqP[oc0 + i],  tot);
  }
}
__device__ void stats2(float v0, float v1, double* sumP, double* sqP, int oc0){
  __shared__ double sred2[4][4];
  const int w = threadIdx.x >> 6;
  float vv[2] = {v0, v1};
  #pragma unroll
  for (int i = 0; i < 2; i++){
    double d = (double)vv[i];
    double s = wredSumD(d);
    double q = wredSumD(d * d);
    if ((threadIdx.x & 63) == 0){ sred2[w][i] = s; sred2[w][2 + i] = q; }
  }
  __syncthreads();
  if (threadIdx.x < 4){
    double tot = sred2[0][threadIdx.x] + sred2[1][threadIdx.x]
               + sred2[2][threadIdx.x] + sred2[3][threadIdx.x];
    int i = threadIdx.x & 1;
    if (threadIdx.x < 2) atomicAdd(&sumP[oc0 + i], tot);
    else                 atomicAdd(&sqP[oc0 + i],  tot);
  }
}

// --------------- K1: weight recon + KL + zero stats buffers ----------------
// dstat layout (doubles): [0:256) ds_sum [256:512) ds_sq
//   [512:576) bn1_sum [576:640) bn1_sq [640:704) bn2_sum [704:768) bn2_sq
//   [768:1024) bn3_sum [1024:1280) bn3_sq
__global__ __launch_bounds__(1024) void recon_kl_kernel(
    const float* w0, const float* a0, const float* l0, float* f0, int n0,
    const float* w1, const float* a1, const float* l1, float* f1, int n1,
    const float* w2, const float* a2, const float* l2, float* f2, int n2,
    const float* w3, const float* a3, const float* l3, float* f3, int n3,
    float* kl_out, double* dstat)
{
  // zero the stats area (1280 doubles over 4 blocks)
  for (int i = threadIdx.x; i < 320; i += 1024) dstat[blockIdx.x * 320 + i] = 0.0;

  const float* w; const float* aff; const float* lap; float* f; int n;
  int t = blockIdx.x;
  if      (t == 0){ w = w0; aff = a0; lap = l0; f = f0; n = n0; }
  else if (t == 1){ w = w1; aff = a1; lap = l1; f = f1; n = n1; }
  else if (t == 2){ w = w2; aff = a2; lap = l2; f = f2; n = n2; }
  else            { w = w3; aff = a3; lap = l3; f = f3; n = n3; }

  __shared__ float saff[STAGE];
  for (int i = threadIdx.x; i < STAGE; i += 1024) saff[i] = aff[i];

  const float4* w4 = (const float4*)w;
  const float4* l4 = (const float4*)lap;
  float4*       f4 = (float4*)f;
  const int n4 = n >> 2;

  float mn = 3.402823466e38f, mx = -3.402823466e38f, ml = -3.402823466e38f;
  for (int i = threadIdx.x; i < n4; i += 1024){
    float4 v = w4[i];
    mn = fminf(mn, fminf(fminf(v.x, v.y), fminf(v.z, v.w)));
    mx = fmaxf(mx, fmaxf(fmaxf(v.x, v.y), fmaxf(v.z, v.w)));
    float4 u = l4[i];
    ml = fmaxf(ml, fmaxf(fmaxf(u.x, u.y), fmaxf(u.z, u.w)));
  }
  mn = blockMin16(mn); mx = blockMax16(mx); ml = blockMax16(ml);
  const float rng = mx - mn;

  float maxf = -3.402823466e38f;
  for (int i = threadIdx.x; i < n4; i += 1024){
    float4 v = w4[i];
    float4 o;
    float* vp = &v.x; float* op = &o.x;
    #pragma unroll
    for (int k = 0; k < 4; k++){
      float vv = vp[k];
      float q = (vv - mn) / rng * 100.0f;
      int idx = (int)floorf(q);
      float nv = 0.0f;
      if (idx < STAGE){
        int ci = idx < 0 ? 0 : (idx > STAGE - 1 ? STAGE - 1 : idx);
        nv = vv * saff[ci];
      }
      op[k] = nv;
      maxf = fmaxf(maxf, nv);
    }
    f4[i] = o;
  }
  maxf = blockMax16(maxf);

  float se = 0.0f, sel = 0.0f, sef = 0.0f, sq = 0.0f;
  for (int i = threadIdx.x; i < n4; i += 1024){
    float4 u = l4[i];
    float4 fv = f4[i];
    float* up = &u.x; float* fp = &fv.x;
    #pragma unroll
    for (int k = 0; k < 4; k++){
      float e = expf(up[k] - ml);
      se  += e;
      sel += e * up[k];
      sef += e * fp[k];
      sq  += expf(fp[k] - maxf);
    }
  }
  se  = blockSum16(se);
  sel = blockSum16(sel);
  sef = blockSum16(sef);
  sq  = blockSum16(sq);

  if (threadIdx.x == 0){
    kl_out[t] = ((sel - sef) / se - ml - logf(se) + maxf + logf(sq)) / (float)n;
  }
}

// --------------- K2: adder_ds  +  (adder_c1 fused with PEG) ----------------
// blocks [0,1024): adder_ds, 4 oc per block, px chunks of 256 (chunk3: 16)
// blocks [1024,1280): adder_c1+peg, 4 oc, 7-row output tile w/ 9-row halo
__global__ __launch_bounds__(256) void front_kernel(
    const float* __restrict__ x, const float* __restrict__ f_ds,
    const float* __restrict__ f_c1, const float* __restrict__ peg_w,
    float* __restrict__ A, float* __restrict__ T2, double* __restrict__ dS)
{
  const int t = threadIdx.x;
  if (blockIdx.x < 1024){
    const int a = blockIdx.x;
    const int chunk = a & 3, og = (a >> 2) & 63, b = a >> 8;
    const int oc0 = og * 4;
    __shared__ float sw[512];
    for (int k = t; k < 512; k += 256) sw[k] = f_ds[oc0 * 128 + k];
    __syncthreads();
    const int px = chunk * 256 + t;
    float v0 = 0, v1 = 0, v2 = 0, v3 = 0;
    if (px < HW){
      const float* xp = x + (size_t)b * 128 * HW + px;
      float c0 = 0, c1 = 0, c2 = 0, c3 = 0;
      #pragma unroll 4
      for (int c = 0; c < 128; c++){
        float xv = xp[(size_t)c * HW];
        c0 += fabsf(xv - sw[c]);
        c1 += fabsf(xv - sw[128 + c]);
        c2 += fabsf(xv - sw[256 + c]);
        c3 += fabsf(xv - sw[384 + c]);
      }
      v0 = -c0; v1 = -c1; v2 = -c2; v3 = -c3;
      float* op = A + ((size_t)(b * 256 + oc0)) * HW + px;
      op[0] = v0; op[HW] = v1; op[2 * HW] = v2; op[3 * HW] = v3;
    }
    stats4(v0, v1, v2, v3, dS + 0, dS + 256, oc0);
  } else {
    const int a = blockIdx.x - 1024;
    const int rc = a & 3, og = (a >> 2) & 15, b = a >> 6;
    const int oc0 = og * 4;
    __shared__ float swc[512];
    __shared__ float swp[36];
    __shared__ float sT1[4][256];
    for (int k = t; k < 512; k += 256) swc[k] = f_c1[oc0 * 128 + k];
    if (t < 36) swp[t] = peg_w[oc0 * 9 + t];
    __syncthreads();
    // phase 1: T1 over 9-row window (rows rc*7-1 .. rc*7+7), 252 px
    if (t < 252){
      const int rr = t / 28;
      const int col = t - rr * 28;
      const int wr = rc * 7 - 1 + rr;
      float tv0 = 0, tv1 = 0, tv2 = 0, tv3 = 0;
      if (wr >= 0 && wr < 28){
        const float* xp = x + (size_t)b * 128 * HW + wr * 28 + col;
        float c0 = 0, c1 = 0, c2 = 0, c3 = 0;
        #pragma unroll 4
        for (int c = 0; c < 128; c++){
          float xv = xp[(size_t)c * HW];
          c0 += fabsf(xv - swc[c]);
          c1 += fabsf(xv - swc[128 + c]);
          c2 += fabsf(xv - swc[256 + c]);
          c3 += fabsf(xv - swc[384 + c]);
        }
        tv0 = -c0; tv1 = -c1; tv2 = -c2; tv3 = -c3;
      }
      sT1[0][t] = tv0; sT1[1][t] = tv1; sT1[2][t] = tv2; sT1[3][t] = tv3;
    }
    __syncthreads();
    // phase 2: depthwise 3x3 adder over the LDS tile, 196 out px
    float v0 = 0, v1 = 0, v2 = 0, v3 = 0;
    if (t < 196){
      const int r = t / 28, col = t - r * 28;
      float c0 = 0, c1 = 0, c2 = 0, c3 = 0;
      #pragma unroll
      for (int ky = 0; ky < 3; ky++){
        #pragma unroll
        for (int kx = 0; kx < 3; kx++){
          int cc = col + kx - 1;
          bool ok = (cc >= 0) && (cc < 28);
          int idx = ok ? ((r + ky) * 28 + cc) : 0;
          float p0 = ok ? sT1[0][idx] : 0.0f;
          float p1 = ok ? sT1[1][idx] : 0.0f;
          float p2 = ok ? sT1[2][idx] : 0.0f;
          float p3 = ok ? sT1[3][idx] : 0.0f;
          int wk = ky * 3 + kx;
          c0 += fabsf(p0 - swp[wk]);
          c1 += fabsf(p1 - swp[9 + wk]);
          c2 += fabsf(p2 - swp[18 + wk]);
          c3 += fabsf(p3 - swp[27 + wk]);
        }
      }
      v0 = -c0; v1 = -c1; v2 = -c2; v3 = -c3;
      const int opx = (rc * 7 + r) * 28 + col;
      float* op = T2 + ((size_t)(b * 64 + oc0)) * HW + opx;
      op[0] = v0; op[HW] = v1; op[2 * HW] = v2; op[3 * HW] = v3;
    }
    stats4(v0, v1, v2, v3, dS + 512, dS + 576, oc0);
  }
}

// --------------- K3: adder 3x3 (bn1 finalize+apply+relu inline) ------------
__global__ __launch_bounds__(256) void mid3x3_kernel(
    const float* __restrict__ T2, const float* __restrict__ f_c2,
    const float* __restrict__ g1, const float* __restrict__ b1,
    float* __restrict__ T3, double* __restrict__ dS)
{
  const int t = threadIdx.x;
  const int a = blockIdx.x;
  const int chunk = a & 3, og = (a >> 2) & 31, b = a >> 7;
  const int oc0 = og * 2;
  __shared__ float ssc[64], ssb[64];
  __shared__ float sw[1152];
  if (t < 64){
    double s  = dS[512 + t] * (1.0 / 3136.0);
    double vr = dS[576 + t] * (1.0 / 3136.0) - s * s;
    float scale = g1[t] * rsqrtf((float)vr + 1e-5f);
    ssc[t] = scale; ssb[t] = b1[t] - (float)s * scale;
  }
  for (int k = t; k < 1152; k += 256) sw[k] = f_c2[oc0 * 576 + k];
  __syncthreads();

  const int px = chunk * 256 + t;
  float v0 = 0, v1 = 0;
  if (px < HW){
    const int y = px / 28, xc = px - y * 28;
    bool val[9]; int off[9];
    #pragma unroll
    for (int ky = 0; ky < 3; ky++){
      #pragma unroll
      for (int kx = 0; kx < 3; kx++){
        int iy = y + ky - 1, ix = xc + kx - 1;
        bool ok = (iy >= 0) && (iy < 28) && (ix >= 0) && (ix < 28);
        val[ky * 3 + kx] = ok;
        off[ky * 3 + kx] = ok ? iy * 28 + ix : 0;
      }
    }
    float c0 = 0, c1 = 0;
    const float* base = T2 + (size_t)b * 64 * HW;
    for (int c = 0; c < 64; c++){
      const float* bc = base + (size_t)c * HW;
      const float sc_ = ssc[c], bi_ = ssb[c];
      const float* w0 = sw + c * 9;
      const float* w1 = sw + 576 + c * 9;
      #pragma unroll
      for (int k = 0; k < 9; k++){
        float raw = val[k] ? bc[off[k]] : 0.0f;
        float vv  = val[k] ? fmaxf(raw * sc_ + bi_, 0.0f) : 0.0f;
        c0 += fabsf(vv - w0[k]);
        c1 += fabsf(vv - w1[k]);
      }
    }
    v0 = -c0; v1 = -c1;
    T3[((size_t)(b * 64 + oc0)) * HW + px]     = v0;
    T3[((size_t)(b * 64 + oc0 + 1)) * HW + px] = v1;
  }
  stats2(v0, v1, dS + 640, dS + 704, oc0);
}

// --------------- K4: adder 1x1 64->256 (bn2 inline) ------------------------
__global__ __launch_bounds__(256) void back_kernel(
    const float* __restrict__ T3, const float* __restrict__ f_c3,
    const float* __restrict__ g2, const float* __restrict__ b2,
    float* __restrict__ out, double* __restrict__ dS)
{
  const int t = threadIdx.x;
  const int a = blockIdx.x;
  const int chunk = a & 3, og = (a >> 2) & 63, b = a >> 8;
  const int oc0 = og * 4;
  __shared__ float ssc[64], ssb[64], sw[256];
  if (t < 64){
    double s  = dS[640 + t] * (1.0 / 3136.0);
    double vr = dS[704 + t] * (1.0 / 3136.0) - s * s;
    float scale = g2[t] * rsqrtf((float)vr + 1e-5f);
    ssc[t] = scale; ssb[t] = b2[t] - (float)s * scale;
  }
  sw[t] = f_c3[oc0 * 64 + t];
  __syncthreads();

  const int px = chunk * 256 + t;
  float v0 = 0, v1 = 0, v2 = 0, v3 = 0;
  if (px < HW){
    const float* bp = T3 + (size_t)b * 64 * HW + px;
    float c0 = 0, c1 = 0, c2 = 0, c3 = 0;
    #pragma unroll 4
    for (int c = 0; c < 64; c++){
      float raw = bp[(size_t)c * HW];
      float vv = fmaxf(raw * ssc[c] + ssb[c], 0.0f);
      c0 += fabsf(vv - sw[c]);
      c1 += fabsf(vv - sw[64 + c]);
      c2 += fabsf(vv - sw[128 + c]);
      c3 += fabsf(vv - sw[192 + c]);
    }
    v0 = -c0; v1 = -c1; v2 = -c2; v3 = -c3;
    float* op = out + ((size_t)(b * 256 + oc0)) * HW + px;
    op[0] = v0; op[HW] = v1; op[2 * HW] = v2; op[3 * HW] = v3;
  }
  stats4(v0, v1, v2, v3, dS + 768, dS + 1024, oc0);
}

// --------------- K5: bn3 + bnds finalize, residual, relu, kl ---------------
__global__ __launch_bounds__(256) void final_kernel(
    float* __restrict__ out, const float* __restrict__ A,
    const float* __restrict__ g3, const float* __restrict__ b3,
    const float* __restrict__ gds, const float* __restrict__ bds,
    const double* __restrict__ dS, const float* __restrict__ kl)
{
  __shared__ float s3c[256], s3b[256], sdc[256], sdb[256];
  const int t = threadIdx.x;
  {
    double s  = dS[768 + t] * (1.0 / 3136.0);
    double vr = dS[1024 + t] * (1.0 / 3136.0) - s * s;
    float scale = g3[t] * rsqrtf((float)vr + 1e-5f);
    s3c[t] = scale; s3b[t] = b3[t] - (float)s * scale;
    s  = dS[t] * (1.0 / 3136.0);
    vr = dS[256 + t] * (1.0 / 3136.0) - s * s;
    scale = gds[t] * rsqrtf((float)vr + 1e-5f);
    sdc[t] = scale; sdb[t] = bds[t] - (float)s * scale;
  }
  __syncthreads();
  #pragma unroll
  for (int k = 0; k < 4; k++){
    int n = blockIdx.x * 1024 + k * 256 + t;
    int c = (n / HW) & 255;
    float h = out[n], aa = A[n];
    float r = fmaxf(aa * sdc[c] + sdb[c], 0.0f);
    out[n] = fmaxf(h * s3c[c] + s3b[c] + r, 0.0f);
  }
  if (blockIdx.x == 0 && t == 0) out[802816] = kl[0] + kl[1] + kl[2] + kl[3];
}

// ===========================================================================
extern "C" void kernel_launch(void* const* d_in, const int* in_sizes, int n_in,
                              void* d_out, int out_size, void* d_ws, size_t ws_size,
                              hipStream_t stream)
{
  const float* x      = (const float*)d_in[0];
  const float* sw_ds  = (const float*)d_in[1];
  const float* sw_c1  = (const float*)d_in[2];
  const float* sw_c2  = (const float*)d_in[3];
  const float* sw_c3  = (const float*)d_in[4];
  const float* a_ds   = (const float*)d_in[5];
  const float* a_c1   = (const float*)d_in[6];
  const float* a_c2   = (const float*)d_in[7];
  const float* a_c3   = (const float*)d_in[8];
  const float* peg_w  = (const float*)d_in[9];
  const float* bn1_g  = (const float*)d_in[10];
  const float* bn1_b  = (const float*)d_in[11];
  const float* bn2_g  = (const float*)d_in[12];
  const float* bn2_b  = (const float*)d_in[13];
  const float* bn3_g  = (const float*)d_in[14];
  const float* bn3_b  = (const float*)d_in[15];
  const float* bnds_g = (const float*)d_in[16];
  const float* bnds_b = (const float*)d_in[17];
  const float* lap_ds = (const float*)d_in[18];
  const float* lap_c1 = (const float*)d_in[19];
  const float* lap_c2 = (const float*)d_in[20];
  const float* lap_c3 = (const float*)d_in[21];

  float* ws    = (float*)d_ws;
  float* f_ds  = ws;                  // 32768
  float* f_c1  = ws + 32768;          // 8192
  float* f_c2  = ws + 40960;          // 36864
  float* f_c3  = ws + 77824;          // 16384
  float* kl    = ws + 94208;          // 4
  double* dstat= (double*)(ws + 98304);  // 1280 doubles (8B aligned)
  float* A     = ws + 102400;         // 802816
  float* T2    = ws + 905216;         // 200704
  float* T3    = ws + 1105920;        // 200704

  float* out = (float*)d_out;

  recon_kl_kernel<<<4, 1024, 0, stream>>>(
      sw_ds, a_ds, lap_ds, f_ds, 32768,
      sw_c1, a_c1, lap_c1, f_c1, 8192,
      sw_c2, a_c2, lap_c2, f_c2, 36864,
      sw_c3, a_c3, lap_c3, f_c3, 16384, kl, dstat);

  front_kernel<<<1280, 256, 0, stream>>>(x, f_ds, f_c1, peg_w, A, T2, dstat);

  mid3x3_kernel<<<512, 256, 0, stream>>>(T2, f_c2, bn1_g, bn1_b, T3, dstat);

  back_kernel<<<1024, 256, 0, stream>>>(T3, f_c3, bn2_g, bn2_b, out, dstat);

  final_kernel<<<784, 256, 0, stream>>>(out, A, bn3_g, bn3_b, bnds_g, bnds_b,
                                        dstat, kl);
}

// Round 4
// 188.159 us; speedup vs baseline: 2.0774x; 1.0866x over previous
//
#include <hip/hip_runtime.h>
#include <math.h>

// R4: mid3x3 rebuilt — bn1+relu pre-applied into zero-padded T2b (new small
// kernel), making the 9 taps unconditional constant-offset loads; weights via
// wave-uniform (scalar) loads. front ds-branch: 8 oc/block. R3 profile:
// mid3x3 47us @ VALUBusy 30% — redundant bn recompute + cndmask taps.

#define HW 784      // 28*28
#define NB 4
#define STAGE 100

// ---------------- wave reduction helpers (wave64) --------------------------
__device__ __forceinline__ float wredSum(float v){
  for (int o = 32; o > 0; o >>= 1) v += __shfl_down(v, o, 64);
  return v;
}
__device__ __forceinline__ float wredMax(float v){
  for (int o = 32; o > 0; o >>= 1) v = fmaxf(v, __shfl_down(v, o, 64));
  return v;
}
__device__ __forceinline__ float wredMin(float v){
  for (int o = 32; o > 0; o >>= 1) v = fminf(v, __shfl_down(v, o, 64));
  return v;
}
__device__ __forceinline__ double wredSumD(double v){
  for (int o = 32; o > 0; o >>= 1) v += __shfl_down(v, o, 64);
  return v;
}

// blockDim=1024 reductions (recon_kl)
__device__ float blockSum16(float v){
  __shared__ float sh[16];
  __syncthreads();
  v = wredSum(v);
  if ((threadIdx.x & 63) == 0) sh[threadIdx.x >> 6] = v;
  __syncthreads();
  float r = 0.0f;
  #pragma unroll
  for (int i = 0; i < 16; i++) r += sh[i];
  return r;
}
__device__ float blockMax16(float v){
  __shared__ float sh[16];
  __syncthreads();
  v = wredMax(v);
  if ((threadIdx.x & 63) == 0) sh[threadIdx.x >> 6] = v;
  __syncthreads();
  float r = sh[0];
  #pragma unroll
  for (int i = 1; i < 16; i++) r = fmaxf(r, sh[i]);
  return r;
}
__device__ float blockMin16(float v){
  __shared__ float sh[16];
  __syncthreads();
  v = wredMin(v);
  if ((threadIdx.x & 63) == 0) sh[threadIdx.x >> 6] = v;
  __syncthreads();
  float r = sh[0];
  #pragma unroll
  for (int i = 1; i < 16; i++) r = fminf(r, sh[i]);
  return r;
}

// ---- per-block stats: 4 channels, sum + sumsq, double atomics (blockDim 256)
// All 256 threads must call (pass 0 for idle lanes). Safe to call repeatedly.
__device__ void stats4(float v0, float v1, float v2, float v3,
                       double* sumP, double* sqP, int oc0){
  __shared__ double sred[4][8];
  __syncthreads();                     // protect sred across calls
  const int w = threadIdx.x >> 6;
  float vv[4] = {v0, v1, v2, v3};
  #pragma unroll
  for (int i = 0; i < 4; i++){
    double d = (double)vv[i];
    double s = wredSumD(d);
    double q = wredSumD(d * d);
    if ((threadIdx.x & 63) == 0){ sred[w][i] = s; sred[w][4 + i] = q; }
  }
  __syncthreads();
  if (threadIdx.x < 8){
    double tot = sred[0][threadIdx.x] + sred[1][threadIdx.x]
               + sred[2][threadIdx.x] + sred[3][threadIdx.x];
    int i = threadIdx.x & 3;
    if (threadIdx.x < 4) atomicAdd(&sumP[oc0 + i], tot);
    else                 atomicAdd(&sqP[oc0 + i],  tot);
  }
}
__device__ void stats2(float v0, float v1, double* sumP, double* sqP, int oc0){
  __shared__ double sred2[4][4];
  __syncthreads();
  const int w = threadIdx.x >> 6;
  float vv[2] = {v0, v1};
  #pragma unroll
  for (int i = 0; i < 2; i++){
    double d = (double)vv[i];
    double s = wredSumD(d);
    double q = wredSumD(d * d);
    if ((threadIdx.x & 63) == 0){ sred2[w][i] = s; sred2[w][2 + i] = q; }
  }
  __syncthreads();
  if (threadIdx.x < 4){
    double tot = sred2[0][threadIdx.x] + sred2[1][threadIdx.x]
               + sred2[2][threadIdx.x] + sred2[3][threadIdx.x];
    int i = threadIdx.x & 1;
    if (threadIdx.x < 2) atomicAdd(&sumP[oc0 + i], tot);
    else                 atomicAdd(&sqP[oc0 + i],  tot);
  }
}

// --------------- K1: weight recon + KL + zero stats buffers ----------------
// dstat layout (doubles): [0:256) ds_sum [256:512) ds_sq
//   [512:576) bn1_sum [576:640) bn1_sq [640:704) bn2_sum [704:768) bn2_sq
//   [768:1024) bn3_sum [1024:1280) bn3_sq
__global__ __launch_bounds__(1024) void recon_kl_kernel(
    const float* w0, const float* a0, const float* l0, float* f0, int n0,
    const float* w1, const float* a1, const float* l1, float* f1, int n1,
    const float* w2, const float* a2, const float* l2, float* f2, int n2,
    const float* w3, const float* a3, const float* l3, float* f3, int n3,
    float* kl_out, double* dstat)
{
  for (int i = threadIdx.x; i < 320; i += 1024) dstat[blockIdx.x * 320 + i] = 0.0;

  const float* w; const float* aff; const float* lap; float* f; int n;
  int t = blockIdx.x;
  if      (t == 0){ w = w0; aff = a0; lap = l0; f = f0; n = n0; }
  else if (t == 1){ w = w1; aff = a1; lap = l1; f = f1; n = n1; }
  else if (t == 2){ w = w2; aff = a2; lap = l2; f = f2; n = n2; }
  else            { w = w3; aff = a3; lap = l3; f = f3; n = n3; }

  __shared__ float saff[STAGE];
  for (int i = threadIdx.x; i < STAGE; i += 1024) saff[i] = aff[i];

  const float4* w4 = (const float4*)w;
  const float4* l4 = (const float4*)lap;
  float4*       f4 = (float4*)f;
  const int n4 = n >> 2;

  float mn = 3.402823466e38f, mx = -3.402823466e38f, ml = -3.402823466e38f;
  for (int i = threadIdx.x; i < n4; i += 1024){
    float4 v = w4[i];
    mn = fminf(mn, fminf(fminf(v.x, v.y), fminf(v.z, v.w)));
    mx = fmaxf(mx, fmaxf(fmaxf(v.x, v.y), fmaxf(v.z, v.w)));
    float4 u = l4[i];
    ml = fmaxf(ml, fmaxf(fmaxf(u.x, u.y), fmaxf(u.z, u.w)));
  }
  mn = blockMin16(mn); mx = blockMax16(mx); ml = blockMax16(ml);
  const float rng = mx - mn;

  float maxf = -3.402823466e38f;
  for (int i = threadIdx.x; i < n4; i += 1024){
    float4 v = w4[i];
    float4 o;
    float* vp = &v.x; float* op = &o.x;
    #pragma unroll
    for (int k = 0; k < 4; k++){
      float vv = vp[k];
      float q = (vv - mn) / rng * 100.0f;
      int idx = (int)floorf(q);
      float nv = 0.0f;
      if (idx < STAGE){
        int ci = idx < 0 ? 0 : (idx > STAGE - 1 ? STAGE - 1 : idx);
        nv = vv * saff[ci];
      }
      op[k] = nv;
      maxf = fmaxf(maxf, nv);
    }
    f4[i] = o;
  }
  maxf = blockMax16(maxf);

  float se = 0.0f, sel = 0.0f, sef = 0.0f, sq = 0.0f;
  for (int i = threadIdx.x; i < n4; i += 1024){
    float4 u = l4[i];
    float4 fv = f4[i];
    float* up = &u.x; float* fp = &fv.x;
    #pragma unroll
    for (int k = 0; k < 4; k++){
      float e = expf(up[k] - ml);
      se  += e;
      sel += e * up[k];
      sef += e * fp[k];
      sq  += expf(fp[k] - maxf);
    }
  }
  se  = blockSum16(se);
  sel = blockSum16(sel);
  sef = blockSum16(sef);
  sq  = blockSum16(sq);

  if (threadIdx.x == 0){
    kl_out[t] = ((sel - sef) / se - ml - logf(se) + maxf + logf(sq)) / (float)n;
  }
}

// --------------- K2: adder_ds  +  (adder_c1 fused with PEG) ----------------
// blocks [0,512): adder_ds, 8 oc per block, px chunks of 256
// blocks [512,768): adder_c1+peg, 4 oc, 7-row output tile w/ 9-row halo
__global__ __launch_bounds__(256) void front_kernel(
    const float* __restrict__ x, const float* __restrict__ f_ds,
    const float* __restrict__ f_c1, const float* __restrict__ peg_w,
    float* __restrict__ A, float* __restrict__ T2, double* __restrict__ dS)
{
  const int t = threadIdx.x;
  if (blockIdx.x < 512){
    const int a = blockIdx.x;
    const int chunk = a & 3, og = (a >> 2) & 31, b = a >> 7;
    const int oc0 = og * 8;
    __shared__ float sw[1024];
    for (int k = t; k < 1024; k += 256) sw[k] = f_ds[oc0 * 128 + k];
    __syncthreads();
    const int px = chunk * 256 + t;
    float v0=0,v1=0,v2=0,v3=0,v4=0,v5=0,v6=0,v7=0;
    if (px < HW){
      const float* xp = x + (size_t)b * 128 * HW + px;
      float c0=0,c1=0,c2=0,c3=0,c4=0,c5=0,c6=0,c7=0;
      #pragma unroll 4
      for (int c = 0; c < 128; c++){
        float xv = xp[(size_t)c * HW];
        c0 += fabsf(xv - sw[c]);
        c1 += fabsf(xv - sw[128 + c]);
        c2 += fabsf(xv - sw[256 + c]);
        c3 += fabsf(xv - sw[384 + c]);
        c4 += fabsf(xv - sw[512 + c]);
        c5 += fabsf(xv - sw[640 + c]);
        c6 += fabsf(xv - sw[768 + c]);
        c7 += fabsf(xv - sw[896 + c]);
      }
      v0=-c0; v1=-c1; v2=-c2; v3=-c3; v4=-c4; v5=-c5; v6=-c6; v7=-c7;
      float* op = A + ((size_t)(b * 256 + oc0)) * HW + px;
      op[0]=v0; op[HW]=v1; op[2*HW]=v2; op[3*HW]=v3;
      op[4*HW]=v4; op[5*HW]=v5; op[6*HW]=v6; op[7*HW]=v7;
    }
    stats4(v0, v1, v2, v3, dS + 0, dS + 256, oc0);
    stats4(v4, v5, v6, v7, dS + 0, dS + 256, oc0 + 4);
  } else {
    const int a = blockIdx.x - 512;
    const int rc = a & 3, og = (a >> 2) & 15, b = a >> 6;
    const int oc0 = og * 4;
    __shared__ float swc[512];
    __shared__ float swp[36];
    __shared__ float sT1[4][256];
    for (int k = t; k < 512; k += 256) swc[k] = f_c1[oc0 * 128 + k];
    if (t < 36) swp[t] = peg_w[oc0 * 9 + t];
    __syncthreads();
    if (t < 252){
      const int rr = t / 28;
      const int col = t - rr * 28;
      const int wr = rc * 7 - 1 + rr;
      float tv0 = 0, tv1 = 0, tv2 = 0, tv3 = 0;
      if (wr >= 0 && wr < 28){
        const float* xp = x + (size_t)b * 128 * HW + wr * 28 + col;
        float c0 = 0, c1 = 0, c2 = 0, c3 = 0;
        #pragma unroll 4
        for (int c = 0; c < 128; c++){
          float xv = xp[(size_t)c * HW];
          c0 += fabsf(xv - swc[c]);
          c1 += fabsf(xv - swc[128 + c]);
          c2 += fabsf(xv - swc[256 + c]);
          c3 += fabsf(xv - swc[384 + c]);
        }
        tv0 = -c0; tv1 = -c1; tv2 = -c2; tv3 = -c3;
      }
      sT1[0][t] = tv0; sT1[1][t] = tv1; sT1[2][t] = tv2; sT1[3][t] = tv3;
    }
    __syncthreads();
    float v0 = 0, v1 = 0, v2 = 0, v3 = 0;
    if (t < 196){
      const int r = t / 28, col = t - r * 28;
      float c0 = 0, c1 = 0, c2 = 0, c3 = 0;
      #pragma unroll
      for (int ky = 0; ky < 3; ky++){
        #pragma unroll
        for (int kx = 0; kx < 3; kx++){
          int cc = col + kx - 1;
          bool ok = (cc >= 0) && (cc < 28);
          int idx = ok ? ((r + ky) * 28 + cc) : 0;
          float p0 = ok ? sT1[0][idx] : 0.0f;
          float p1 = ok ? sT1[1][idx] : 0.0f;
          float p2 = ok ? sT1[2][idx] : 0.0f;
          float p3 = ok ? sT1[3][idx] : 0.0f;
          int wk = ky * 3 + kx;
          c0 += fabsf(p0 - swp[wk]);
          c1 += fabsf(p1 - swp[9 + wk]);
          c2 += fabsf(p2 - swp[18 + wk]);
          c3 += fabsf(p3 - swp[27 + wk]);
        }
      }
      v0 = -c0; v1 = -c1; v2 = -c2; v3 = -c3;
      const int opx = (rc * 7 + r) * 28 + col;
      float* op = T2 + ((size_t)(b * 64 + oc0)) * HW + opx;
      op[0] = v0; op[HW] = v1; op[2 * HW] = v2; op[3 * HW] = v3;
    }
    stats4(v0, v1, v2, v3, dS + 512, dS + 576, oc0);
  }
}

// --------------- K2b: bn1 finalize + apply + relu -> padded T2b ------------
// T2b layout: (b, c, row 0..29, col 0..31); row0/29 + col0/29 are zero pad,
// interior [1..28]x[1..28] = relu(bn1(T2)). Cols 30,31 unused (zeroed).
__global__ __launch_bounds__(256) void bnapply_pad_kernel(
    const float* __restrict__ T2, float* __restrict__ T2b,
    const float* __restrict__ g1, const float* __restrict__ b1,
    const double* __restrict__ dS)
{
  const int a = blockIdx.x;           // b*64 + c
  const int c = a & 63, b = a >> 6;
  __shared__ float ssc, ssb;
  if (threadIdx.x == 0){
    double s  = dS[512 + c] * (1.0 / 3136.0);
    double vr = dS[576 + c] * (1.0 / 3136.0) - s * s;
    float scale = g1[c] * rsqrtf((float)vr + 1e-5f);
    ssc = scale; ssb = b1[c] - (float)s * scale;
  }
  __syncthreads();
  const float sc_ = ssc, bi_ = ssb;
  const float* src = T2 + (size_t)a * HW;
  float* dst = T2b + (size_t)a * 960;
  for (int i = threadIdx.x; i < 960; i += 256){
    int row = i >> 5, col = i & 31;
    float v = 0.0f;
    if (row >= 1 && row <= 28 && col >= 1 && col <= 28)
      v = fmaxf(src[(row - 1) * 28 + (col - 1)] * sc_ + bi_, 0.0f);
    dst[i] = v;
  }
}

// --------------- K3: adder 3x3 over padded T2b -----------------------------
// 9 unconditional taps at constant offsets; weights via wave-uniform loads.
__global__ __launch_bounds__(256) void mid3x3_kernel(
    const float* __restrict__ T2b, const float* __restrict__ f_c2,
    float* __restrict__ T3, double* __restrict__ dS)
{
  const int t = threadIdx.x;
  const int a = blockIdx.x;
  const int chunk = a & 3, og = (a >> 2) & 31, b = a >> 7;
  const int oc0 = og * 2;
  const float* __restrict__ wA = f_c2 + oc0 * 576;
  const float* __restrict__ wB = wA + 576;

  float v0 = 0, v1 = 0;
  const int px = chunk * 196 + t;
  if (t < 196){
    const int y = px / 28, xc = px - y * 28;
    const float* base = T2b + (size_t)b * 64 * 960 + y * 32 + xc;
    float c0 = 0, c1 = 0;
    #pragma unroll 2
    for (int c = 0; c < 64; c++){
      const float* p = base + c * 960;
      float t0 = p[0],  t1 = p[1],  t2 = p[2];
      float t3 = p[32], t4 = p[33], t5 = p[34];
      float t6 = p[64], t7 = p[65], t8 = p[66];
      const float* wa = wA + c * 9;
      const float* wb = wB + c * 9;
      c0 += fabsf(t0 - wa[0]) + fabsf(t1 - wa[1]) + fabsf(t2 - wa[2])
          + fabsf(t3 - wa[3]) + fabsf(t4 - wa[4]) + fabsf(t5 - wa[5])
          + fabsf(t6 - wa[6]) + fabsf(t7 - wa[7]) + fabsf(t8 - wa[8]);
      c1 += fabsf(t0 - wb[0]) + fabsf(t1 - wb[1]) + fabsf(t2 - wb[2])
          + fabsf(t3 - wb[3]) + fabsf(t4 - wb[4]) + fabsf(t5 - wb[5])
          + fabsf(t6 - wb[6]) + fabsf(t7 - wb[7]) + fabsf(t8 - wb[8]);
    }
    v0 = -c0; v1 = -c1;
    T3[((size_t)(b * 64 + oc0)) * HW + px]     = v0;
    T3[((size_t)(b * 64 + oc0 + 1)) * HW + px] = v1;
  }
  stats2(v0, v1, dS + 640, dS + 704, oc0);
}

// --------------- K4: adder 1x1 64->256 (bn2 inline) ------------------------
__global__ __launch_bounds__(256) void back_kernel(
    const float* __restrict__ T3, const float* __restrict__ f_c3,
    const float* __restrict__ g2, const float* __restrict__ b2,
    float* __restrict__ out, double* __restrict__ dS)
{
  const int t = threadIdx.x;
  const int a = blockIdx.x;
  const int chunk = a & 3, og = (a >> 2) & 63, b = a >> 8;
  const int oc0 = og * 4;
  __shared__ float ssc[64], ssb[64], sw[256];
  if (t < 64){
    double s  = dS[640 + t] * (1.0 / 3136.0);
    double vr = dS[704 + t] * (1.0 / 3136.0) - s * s;
    float scale = g2[t] * rsqrtf((float)vr + 1e-5f);
    ssc[t] = scale; ssb[t] = b2[t] - (float)s * scale;
  }
  sw[t] = f_c3[oc0 * 64 + t];
  __syncthreads();

  const int px = chunk * 256 + t;
  float v0 = 0, v1 = 0, v2 = 0, v3 = 0;
  if (px < HW){
    const float* bp = T3 + (size_t)b * 64 * HW + px;
    float c0 = 0, c1 = 0, c2 = 0, c3 = 0;
    #pragma unroll 4
    for (int c = 0; c < 64; c++){
      float raw = bp[(size_t)c * HW];
      float vv = fmaxf(raw * ssc[c] + ssb[c], 0.0f);
      c0 += fabsf(vv - sw[c]);
      c1 += fabsf(vv - sw[64 + c]);
      c2 += fabsf(vv - sw[128 + c]);
      c3 += fabsf(vv - sw[192 + c]);
    }
    v0 = -c0; v1 = -c1; v2 = -c2; v3 = -c3;
    float* op = out + ((size_t)(b * 256 + oc0)) * HW + px;
    op[0] = v0; op[HW] = v1; op[2 * HW] = v2; op[3 * HW] = v3;
  }
  stats4(v0, v1, v2, v3, dS + 768, dS + 1024, oc0);
}

// --------------- K5: bn3 + bnds finalize, residual, relu, kl ---------------
__global__ __launch_bounds__(256) void final_kernel(
    float* __restrict__ out, const float* __restrict__ A,
    const float* __restrict__ g3, const float* __restrict__ b3,
    const float* __restrict__ gds, const float* __restrict__ bds,
    const double* __restrict__ dS, const float* __restrict__ kl)
{
  __shared__ float s3c[256], s3b[256], sdc[256], sdb[256];
  const int t = threadIdx.x;
  {
    double s  = dS[768 + t] * (1.0 / 3136.0);
    double vr = dS[1024 + t] * (1.0 / 3136.0) - s * s;
    float scale = g3[t] * rsqrtf((float)vr + 1e-5f);
    s3c[t] = scale; s3b[t] = b3[t] - (float)s * scale;
    s  = dS[t] * (1.0 / 3136.0);
    vr = dS[256 + t] * (1.0 / 3136.0) - s * s;
    scale = gds[t] * rsqrtf((float)vr + 1e-5f);
    sdc[t] = scale; sdb[t] = bds[t] - (float)s * scale;
  }
  __syncthreads();
  #pragma unroll
  for (int k = 0; k < 4; k++){
    int n = blockIdx.x * 1024 + k * 256 + t;
    int c = (n / HW) & 255;
    float h = out[n], aa = A[n];
    float r = fmaxf(aa * sdc[c] + sdb[c], 0.0f);
    out[n] = fmaxf(h * s3c[c] + s3b[c] + r, 0.0f);
  }
  if (blockIdx.x == 0 && t == 0) out[802816] = kl[0] + kl[1] + kl[2] + kl[3];
}

// ===========================================================================
extern "C" void kernel_launch(void* const* d_in, const int* in_sizes, int n_in,
                              void* d_out, int out_size, void* d_ws, size_t ws_size,
                              hipStream_t stream)
{
  const float* x      = (const float*)d_in[0];
  const float* sw_ds  = (const float*)d_in[1];
  const float* sw_c1  = (const float*)d_in[2];
  const float* sw_c2  = (const float*)d_in[3];
  const float* sw_c3  = (const float*)d_in[4];
  const float* a_ds   = (const float*)d_in[5];
  const float* a_c1   = (const float*)d_in[6];
  const float* a_c2   = (const float*)d_in[7];
  const float* a_c3   = (const float*)d_in[8];
  const float* peg_w  = (const float*)d_in[9];
  const float* bn1_g  = (const float*)d_in[10];
  const float* bn1_b  = (const float*)d_in[11];
  const float* bn2_g  = (const float*)d_in[12];
  const float* bn2_b  = (const float*)d_in[13];
  const float* bn3_g  = (const float*)d_in[14];
  const float* bn3_b  = (const float*)d_in[15];
  const float* bnds_g = (const float*)d_in[16];
  const float* bnds_b = (const float*)d_in[17];
  const float* lap_ds = (const float*)d_in[18];
  const float* lap_c1 = (const float*)d_in[19];
  const float* lap_c2 = (const float*)d_in[20];
  const float* lap_c3 = (const float*)d_in[21];

  float* ws    = (float*)d_ws;
  float* f_ds  = ws;                  // 32768
  float* f_c1  = ws + 32768;          // 8192
  float* f_c2  = ws + 40960;          // 36864
  float* f_c3  = ws + 77824;          // 16384
  float* kl    = ws + 94208;          // 4
  double* dstat= (double*)(ws + 98304);  // 1280 doubles
  float* A     = ws + 102400;         // 802816
  float* T2    = ws + 905216;         // 200704
  float* T3    = ws + 1105920;        // 200704
  float* T2b   = ws + 1306624;        // 245760 (4*64*30*32)

  float* out = (float*)d_out;

  recon_kl_kernel<<<4, 1024, 0, stream>>>(
      sw_ds, a_ds, lap_ds, f_ds, 32768,
      sw_c1, a_c1, lap_c1, f_c1, 8192,
      sw_c2, a_c2, lap_c2, f_c2, 36864,
      sw_c3, a_c3, lap_c3, f_c3, 16384, kl, dstat);

  front_kernel<<<768, 256, 0, stream>>>(x, f_ds, f_c1, peg_w, A, T2, dstat);

  bnapply_pad_kernel<<<256, 256, 0, stream>>>(T2, T2b, bn1_g, bn1_b, dstat);

  mid3x3_kernel<<<512, 256, 0, stream>>>(T2b, f_c2, T3, dstat);

  back_kernel<<<1024, 256, 0, stream>>>(T3, f_c3, bn2_g, bn2_b, out, dstat);

  final_kernel<<<784, 256, 0, stream>>>(out, A, bn3_g, bn3_b, bnds_g, bnds_b,
                                        dstat, kl);
}

// Round 5
// 171.823 us; speedup vs baseline: 2.2749x; 1.0951x over previous
//
#include <hip/hip_runtime.h>
#include <math.h>

// R5: recon distributed into consumers. minmax_kernel (grid 64) computes
// per-block partial min/max into disjoint slots; front/back blocks recon
// their own weight slices inline into LDS. f_c2 alone is materialized (for
// mid3x3's wave-uniform weight loads) by 80 rider blocks in front. KL uses
// shift-free sums (se,sel,sef,sq per tensor; fp32-safe since lap<=~22,
// |f|<=~1) via double atomics, finalized in final_kernel.

#define HW 784      // 28*28
#define NB 4
#define STAGE 100

// ---------------- wave/block reduction helpers (wave64) --------------------
__device__ __forceinline__ float wredSum(float v){
  for (int o = 32; o > 0; o >>= 1) v += __shfl_down(v, o, 64);
  return v;
}
__device__ __forceinline__ float wredMax(float v){
  for (int o = 32; o > 0; o >>= 1) v = fmaxf(v, __shfl_down(v, o, 64));
  return v;
}
__device__ __forceinline__ float wredMin(float v){
  for (int o = 32; o > 0; o >>= 1) v = fminf(v, __shfl_down(v, o, 64));
  return v;
}
__device__ __forceinline__ double wredSumD(double v){
  for (int o = 32; o > 0; o >>= 1) v += __shfl_down(v, o, 64);
  return v;
}

// blockDim = 256 (4 waves)
__device__ float blockMin4(float v){
  __shared__ float shn[4];
  __syncthreads();
  v = wredMin(v);
  if ((threadIdx.x & 63) == 0) shn[threadIdx.x >> 6] = v;
  __syncthreads();
  return fminf(fminf(shn[0], shn[1]), fminf(shn[2], shn[3]));
}
__device__ float blockMax4(float v){
  __shared__ float shx[4];
  __syncthreads();
  v = wredMax(v);
  if ((threadIdx.x & 63) == 0) shx[threadIdx.x >> 6] = v;
  __syncthreads();
  return fmaxf(fmaxf(shx[0], shx[1]), fmaxf(shx[2], shx[3]));
}

// ---- per-block BN stats: 4 channels, sum+sumsq, double atomics (256 thr) --
__device__ void stats4(float v0, float v1, float v2, float v3,
                       double* sumP, double* sqP, int oc0){
  __shared__ double sred[4][8];
  __syncthreads();
  const int w = threadIdx.x >> 6;
  float vv[4] = {v0, v1, v2, v3};
  #pragma unroll
  for (int i = 0; i < 4; i++){
    double d = (double)vv[i];
    double s = wredSumD(d);
    double q = wredSumD(d * d);
    if ((threadIdx.x & 63) == 0){ sred[w][i] = s; sred[w][4 + i] = q; }
  }
  __syncthreads();
  if (threadIdx.x < 8){
    double tot = sred[0][threadIdx.x] + sred[1][threadIdx.x]
               + sred[2][threadIdx.x] + sred[3][threadIdx.x];
    int i = threadIdx.x & 3;
    if (threadIdx.x < 4) atomicAdd(&sumP[oc0 + i], tot);
    else                 atomicAdd(&sqP[oc0 + i],  tot);
  }
}
__device__ void stats2(float v0, float v1, double* sumP, double* sqP, int oc0){
  __shared__ double sred2[4][4];
  __syncthreads();
  const int w = threadIdx.x >> 6;
  float vv[2] = {v0, v1};
  #pragma unroll
  for (int i = 0; i < 2; i++){
    double d = (double)vv[i];
    double s = wredSumD(d);
    double q = wredSumD(d * d);
    if ((threadIdx.x & 63) == 0){ sred2[w][i] = s; sred2[w][2 + i] = q; }
  }
  __syncthreads();
  if (threadIdx.x < 4){
    double tot = sred2[0][threadIdx.x] + sred2[1][threadIdx.x]
               + sred2[2][threadIdx.x] + sred2[3][threadIdx.x];
    int i = threadIdx.x & 1;
    if (threadIdx.x < 2) atomicAdd(&sumP[oc0 + i], tot);
    else                 atomicAdd(&sqP[oc0 + i],  tot);
  }
}

// ---- KL partial accumulation: 4 sums -> 4 double atomics (256 thr) --------
__device__ void klAccum(float se, float sel, float sef, float sq, double* dst){
  __shared__ double kls[4][4];
  __syncthreads();
  const int w = threadIdx.x >> 6;
  double a0 = wredSumD((double)se);
  double a1 = wredSumD((double)sel);
  double a2 = wredSumD((double)sef);
  double a3 = wredSumD((double)sq);
  if ((threadIdx.x & 63) == 0){
    kls[w][0] = a0; kls[w][1] = a1; kls[w][2] = a2; kls[w][3] = a3;
  }
  __syncthreads();
  if (threadIdx.x < 4){
    double tot = kls[0][threadIdx.x] + kls[1][threadIdx.x]
               + kls[2][threadIdx.x] + kls[3][threadIdx.x];
    atomicAdd(&dst[threadIdx.x], tot);
  }
}

// ---- bin reconstruction (reference op order; exact bin indices) -----------
__device__ __forceinline__ float reconv(float vv, float mn, float rng,
                                        const float* saff){
  float q = (vv - mn) / rng * 100.0f;
  int idx = (int)floorf(q);
  float nv = 0.0f;
  if (idx < STAGE){
    int ci = idx < 0 ? 0 : (idx > STAGE - 1 ? STAGE - 1 : idx);
    nv = vv * saff[ci];
  }
  return nv;
}

// ---- reduce 16 per-block minmax partials (race-free, no atomics) ----------
__device__ __forceinline__ void mmReduce(const float* mmbuf, int tens,
                                         float& mn, float& mx){
  mn = 3.402823466e38f; mx = -3.402823466e38f;
  #pragma unroll
  for (int k = 0; k < 16; k++){
    mn = fminf(mn, mmbuf[tens * 32 + k]);
    mx = fmaxf(mx, mmbuf[tens * 32 + 16 + k]);
  }
}

// --------------- K0: partial min/max of 4 weight tensors + zero stats ------
// grid = 64: tensor = blk>>4, slot = blk&15. Also zeroes dstat (1344 dbl).
// dstat layout: [0:256) ds_sum [256:512) ds_sq [512:576) bn1_s [576:640) bn1_q
//   [640:704) bn2_s [704:768) bn2_q [768:1024) bn3_s [1024:1280) bn3_q
//   [1280:1296) kl: tensor*4 + {se, sel, sef, sq}
__global__ __launch_bounds__(256) void minmax_kernel(
    const float* w0, int n0, const float* w1, int n1,
    const float* w2, int n2, const float* w3, int n3,
    float* mmbuf, double* dstat)
{
  if (threadIdx.x < 21) dstat[blockIdx.x * 21 + threadIdx.x] = 0.0;
  const int tens = blockIdx.x >> 4, slot = blockIdx.x & 15;
  const float* w; int n;
  if      (tens == 0){ w = w0; n = n0; }
  else if (tens == 1){ w = w1; n = n1; }
  else if (tens == 2){ w = w2; n = n2; }
  else               { w = w3; n = n3; }
  float mn = 3.402823466e38f, mx = -3.402823466e38f;
  for (int i = slot * 256 + threadIdx.x; i < n; i += 4096){
    float v = w[i];
    mn = fminf(mn, v); mx = fmaxf(mx, v);
  }
  mn = blockMin4(mn); mx = blockMax4(mx);
  if (threadIdx.x == 0){
    mmbuf[tens * 32 + slot]      = mn;
    mmbuf[tens * 32 + 16 + slot] = mx;
  }
}

// --------------- K1: front — adder_ds + (adder_c1+PEG) + f_c2/KL riders ----
// blocks [0,512): adder_ds, 8 oc, px chunk of 196 (inline recon of slice)
// blocks [512,768): adder_c1+peg, 4 oc, 7-row tile (inline recon)
// blocks [768,832): recon+write f_c2 row (576 elems) + KL partial (t2)
// blocks [832,848): recon f_c3 slice (1024) + KL partial (t3)
__global__ __launch_bounds__(256) void front_kernel(
    const float* __restrict__ x,
    const float* __restrict__ w_ds, const float* __restrict__ aff_ds,
    const float* __restrict__ lap_ds,
    const float* __restrict__ w_c1, const float* __restrict__ aff_c1,
    const float* __restrict__ lap_c1,
    const float* __restrict__ w_c2, const float* __restrict__ aff_c2,
    const float* __restrict__ lap_c2, float* __restrict__ f_c2,
    const float* __restrict__ w_c3, const float* __restrict__ aff_c3,
    const float* __restrict__ lap_c3,
    const float* __restrict__ peg_w, const float* __restrict__ mmbuf,
    float* __restrict__ A, float* __restrict__ T2, double* __restrict__ dS)
{
  const int t = threadIdx.x;
  if (blockIdx.x < 512){
    // ---------------- adder_ds ----------------
    const int a = blockIdx.x;
    const int chunk = a & 3, og = (a >> 2) & 31, b = a >> 7;
    const int oc0 = og * 8;
    __shared__ float saff[STAGE];
    __shared__ float sw[1024];
    if (t < STAGE) saff[t] = aff_ds[t];
    float mn, mx; mmReduce(mmbuf, 0, mn, mx);
    const float rng = mx - mn;
    __syncthreads();
    for (int k = t; k < 1024; k += 256)
      sw[k] = reconv(w_ds[oc0 * 128 + k], mn, rng, saff);
    __syncthreads();

    const int px = chunk * 196 + t;
    float v0=0,v1=0,v2=0,v3=0,v4=0,v5=0,v6=0,v7=0;
    if (t < 196){
      const float* xp = x + (size_t)b * 128 * HW + px;
      float c0=0,c1=0,c2=0,c3=0,c4=0,c5=0,c6=0,c7=0;
      #pragma unroll 4
      for (int c = 0; c < 128; c++){
        float xv = xp[(size_t)c * HW];
        c0 += fabsf(xv - sw[c]);
        c1 += fabsf(xv - sw[128 + c]);
        c2 += fabsf(xv - sw[256 + c]);
        c3 += fabsf(xv - sw[384 + c]);
        c4 += fabsf(xv - sw[512 + c]);
        c5 += fabsf(xv - sw[640 + c]);
        c6 += fabsf(xv - sw[768 + c]);
        c7 += fabsf(xv - sw[896 + c]);
      }
      v0=-c0; v1=-c1; v2=-c2; v3=-c3; v4=-c4; v5=-c5; v6=-c6; v7=-c7;
      float* op = A + ((size_t)(b * 256 + oc0)) * HW + px;
      op[0]=v0; op[HW]=v1; op[2*HW]=v2; op[3*HW]=v3;
      op[4*HW]=v4; op[5*HW]=v5; op[6*HW]=v6; op[7*HW]=v7;
    }
    stats4(v0, v1, v2, v3, dS + 0, dS + 256, oc0);
    stats4(v4, v5, v6, v7, dS + 0, dS + 256, oc0 + 4);

    if (b == 0 && chunk == 0){     // KL partial for tensor 0 (own slice)
      float se = 0, sel = 0, sef = 0, sq = 0;
      for (int k = t; k < 1024; k += 256){
        float l = lap_ds[oc0 * 128 + k];
        float e = expf(l);
        se += e; sel += e * l; sef += e * sw[k];
        sq += expf(sw[k]);
      }
      klAccum(se, sel, sef, sq, dS + 1280 + 0);
    }
  } else if (blockIdx.x < 768){
    // ---------------- adder_c1 + PEG ----------------
    const int a = blockIdx.x - 512;
    const int rc = a & 3, og = (a >> 2) & 15, b = a >> 6;
    const int oc0 = og * 4;
    __shared__ float saffc[STAGE];
    __shared__ float swc[512];
    __shared__ float swp[36];
    __shared__ float sT1[4][256];
    if (t < STAGE) saffc[t] = aff_c1[t];
    if (t >= 128 && t < 164) swp[t - 128] = peg_w[oc0 * 9 + (t - 128)];
    float mn, mx; mmReduce(mmbuf, 1, mn, mx);
    const float rng = mx - mn;
    __syncthreads();
    for (int k = t; k < 512; k += 256)
      swc[k] = reconv(w_c1[oc0 * 128 + k], mn, rng, saffc);
    __syncthreads();

    if (t < 252){
      const int rr = t / 28;
      const int col = t - rr * 28;
      const int wr = rc * 7 - 1 + rr;
      float tv0 = 0, tv1 = 0, tv2 = 0, tv3 = 0;
      if (wr >= 0 && wr < 28){
        const float* xp = x + (size_t)b * 128 * HW + wr * 28 + col;
        float c0 = 0, c1 = 0, c2 = 0, c3 = 0;
        #pragma unroll 4
        for (int c = 0; c < 128; c++){
          float xv = xp[(size_t)c * HW];
          c0 += fabsf(xv - swc[c]);
          c1 += fabsf(xv - swc[128 + c]);
          c2 += fabsf(xv - swc[256 + c]);
          c3 += fabsf(xv - swc[384 + c]);
        }
        tv0 = -c0; tv1 = -c1; tv2 = -c2; tv3 = -c3;
      }
      sT1[0][t] = tv0; sT1[1][t] = tv1; sT1[2][t] = tv2; sT1[3][t] = tv3;
    }
    __syncthreads();
    float v0 = 0, v1 = 0, v2 = 0, v3 = 0;
    if (t < 196){
      const int r = t / 28, col = t - r * 28;
      float c0 = 0, c1 = 0, c2 = 0, c3 = 0;
      #pragma unroll
      for (int ky = 0; ky < 3; ky++){
        #pragma unroll
        for (int kx = 0; kx < 3; kx++){
          int cc = col + kx - 1;
          bool ok = (cc >= 0) && (cc < 28);
          int idx = ok ? ((r + ky) * 28 + cc) : 0;
          float p0 = ok ? sT1[0][idx] : 0.0f;
          float p1 = ok ? sT1[1][idx] : 0.0f;
          float p2 = ok ? sT1[2][idx] : 0.0f;
          float p3 = ok ? sT1[3][idx] : 0.0f;
          int wk = ky * 3 + kx;
          c0 += fabsf(p0 - swp[wk]);
          c1 += fabsf(p1 - swp[9 + wk]);
          c2 += fabsf(p2 - swp[18 + wk]);
          c3 += fabsf(p3 - swp[27 + wk]);
        }
      }
      v0 = -c0; v1 = -c1; v2 = -c2; v3 = -c3;
      const int opx = (rc * 7 + r) * 28 + col;
      float* op = T2 + ((size_t)(b * 64 + oc0)) * HW + opx;
      op[0] = v0; op[HW] = v1; op[2 * HW] = v2; op[3 * HW] = v3;
    }
    stats4(v0, v1, v2, v3, dS + 512, dS + 576, oc0);

    if (b == 0 && rc == 0){        // KL partial for tensor 1
      float se = 0, sel = 0, sef = 0, sq = 0;
      for (int k = t; k < 512; k += 256){
        float l = lap_c1[oc0 * 128 + k];
        float e = expf(l);
        se += e; sel += e * l; sef += e * swc[k];
        sq += expf(swc[k]);
      }
      klAccum(se, sel, sef, sq, dS + 1280 + 4);
    }
  } else if (blockIdx.x < 832){
    // ---------------- f_c2 writer + KL (tensor 2) ----------------
    const int j = blockIdx.x - 768;          // oc row 0..63, 576 elems
    __shared__ float saff2[STAGE];
    if (t < STAGE) saff2[t] = aff_c2[t];
    float mn, mx; mmReduce(mmbuf, 2, mn, mx);
    const float rng = mx - mn;
    __syncthreads();
    float se = 0, sel = 0, sef = 0, sq = 0;
    for (int k = t; k < 576; k += 256){
      float nv = reconv(w_c2[j * 576 + k], mn, rng, saff2);
      f_c2[j * 576 + k] = nv;
      float l = lap_c2[j * 576 + k];
      float e = expf(l);
      se += e; sel += e * l; sef += e * nv; sq += expf(nv);
    }
    klAccum(se, sel, sef, sq, dS + 1280 + 8);
  } else {
    // ---------------- KL (tensor 3) ----------------
    const int j = blockIdx.x - 832;          // slice of 1024
    __shared__ float saff3[STAGE];
    if (t < STAGE) saff3[t] = aff_c3[t];
    float mn, mx; mmReduce(mmbuf, 3, mn, mx);
    const float rng = mx - mn;
    __syncthreads();
    float se = 0, sel = 0, sef = 0, sq = 0;
    for (int k = t; k < 1024; k += 256){
      float nv = reconv(w_c3[j * 1024 + k], mn, rng, saff3);
      float l = lap_c3[j * 1024 + k];
      float e = expf(l);
      se += e; sel += e * l; sef += e * nv; sq += expf(nv);
    }
    klAccum(se, sel, sef, sq, dS + 1280 + 12);
  }
}

// --------------- K2: bn1 finalize + apply + relu -> padded T2b -------------
// T2b: (b, c, row 0..29, col 0..31); interior [1..28]^2 = relu(bn1(T2)).
__global__ __launch_bounds__(256) void bnapply_pad_kernel(
    const float* __restrict__ T2, float* __restrict__ T2b,
    const float* __restrict__ g1, const float* __restrict__ b1,
    const double* __restrict__ dS)
{
  const int a = blockIdx.x;           // b*64 + c
  const int c = a & 63, b = a >> 6;
  __shared__ float ssc, ssb;
  if (threadIdx.x == 0){
    double s  = dS[512 + c] * (1.0 / 3136.0);
    double vr = dS[576 + c] * (1.0 / 3136.0) - s * s;
    float scale = g1[c] * rsqrtf((float)vr + 1e-5f);
    ssc = scale; ssb = b1[c] - (float)s * scale;
  }
  __syncthreads();
  const float sc_ = ssc, bi_ = ssb;
  const float* src = T2 + (size_t)a * HW;
  float* dst = T2b + (size_t)a * 960;
  for (int i = threadIdx.x; i < 960; i += 256){
    int row = i >> 5, col = i & 31;
    float v = 0.0f;
    if (row >= 1 && row <= 28 && col >= 1 && col <= 28)
      v = fmaxf(src[(row - 1) * 28 + (col - 1)] * sc_ + bi_, 0.0f);
    dst[i] = v;
  }
}

// --------------- K3: adder 3x3 over padded T2b -----------------------------
__global__ __launch_bounds__(256) void mid3x3_kernel(
    const float* __restrict__ T2b, const float* __restrict__ f_c2,
    float* __restrict__ T3, double* __restrict__ dS)
{
  const int t = threadIdx.x;
  const int a = blockIdx.x;
  const int chunk = a & 3, og = (a >> 2) & 31, b = a >> 7;
  const int oc0 = og * 2;
  const float* __restrict__ wA = f_c2 + oc0 * 576;
  const float* __restrict__ wB = wA + 576;

  float v0 = 0, v1 = 0;
  const int px = chunk * 196 + t;
  if (t < 196){
    const int y = px / 28, xc = px - y * 28;
    const float* base = T2b + (size_t)b * 64 * 960 + y * 32 + xc;
    float c0 = 0, c1 = 0;
    #pragma unroll 2
    for (int c = 0; c < 64; c++){
      const float* p = base + c * 960;
      float t0 = p[0],  t1 = p[1],  t2 = p[2];
      float t3 = p[32], t4 = p[33], t5 = p[34];
      float t6 = p[64], t7 = p[65], t8 = p[66];
      const float* wa = wA + c * 9;
      const float* wb = wB + c * 9;
      c0 += fabsf(t0 - wa[0]) + fabsf(t1 - wa[1]) + fabsf(t2 - wa[2])
          + fabsf(t3 - wa[3]) + fabsf(t4 - wa[4]) + fabsf(t5 - wa[5])
          + fabsf(t6 - wa[6]) + fabsf(t7 - wa[7]) + fabsf(t8 - wa[8]);
      c1 += fabsf(t0 - wb[0]) + fabsf(t1 - wb[1]) + fabsf(t2 - wb[2])
          + fabsf(t3 - wb[3]) + fabsf(t4 - wb[4]) + fabsf(t5 - wb[5])
          + fabsf(t6 - wb[6]) + fabsf(t7 - wb[7]) + fabsf(t8 - wb[8]);
    }
    v0 = -c0; v1 = -c1;
    T3[((size_t)(b * 64 + oc0)) * HW + px]     = v0;
    T3[((size_t)(b * 64 + oc0 + 1)) * HW + px] = v1;
  }
  stats2(v0, v1, dS + 640, dS + 704, oc0);
}

// --------------- K4: adder 1x1 64->256 (bn2 inline, inline recon) ----------
__global__ __launch_bounds__(256) void back_kernel(
    const float* __restrict__ T3, const float* __restrict__ w_c3,
    const float* __restrict__ aff_c3, const float* __restrict__ mmbuf,
    const float* __restrict__ g2, const float* __restrict__ b2,
    float* __restrict__ out, double* __restrict__ dS)
{
  const int t = threadIdx.x;
  const int a = blockIdx.x;
  const int chunk = a & 3, og = (a >> 2) & 63, b = a >> 8;
  const int oc0 = og * 4;
  __shared__ float ssc[64], ssb[64], sw[256], saff[STAGE];
  if (t < 64){
    double s  = dS[640 + t] * (1.0 / 3136.0);
    double vr = dS[704 + t] * (1.0 / 3136.0) - s * s;
    float scale = g2[t] * rsqrtf((float)vr + 1e-5f);
    ssc[t] = scale; ssb[t] = b2[t] - (float)s * scale;
  }
  if (t >= 128 && t < 128 + STAGE) saff[t - 128] = aff_c3[t - 128];
  float mn, mx; mmReduce(mmbuf, 3, mn, mx);
  const float rng = mx - mn;
  __syncthreads();
  sw[t] = reconv(w_c3[oc0 * 64 + t], mn, rng, saff);
  __syncthreads();

  const int px = chunk * 196 + t;
  float v0 = 0, v1 = 0, v2 = 0, v3 = 0;
  if (t < 196){
    const float* bp = T3 + (size_t)b * 64 * HW + px;
    float c0 = 0, c1 = 0, c2 = 0, c3 = 0;
    #pragma unroll 4
    for (int c = 0; c < 64; c++){
      float raw = bp[(size_t)c * HW];
      float vv = fmaxf(raw * ssc[c] + ssb[c], 0.0f);
      c0 += fabsf(vv - sw[c]);
      c1 += fabsf(vv - sw[64 + c]);
      c2 += fabsf(vv - sw[128 + c]);
      c3 += fabsf(vv - sw[192 + c]);
    }
    v0 = -c0; v1 = -c1; v2 = -c2; v3 = -c3;
    float* op = out + ((size_t)(b * 256 + oc0)) * HW + px;
    op[0] = v0; op[HW] = v1; op[2 * HW] = v2; op[3 * HW] = v3;
  }
  stats4(v0, v1, v2, v3, dS + 768, dS + 1024, oc0);
}

// --------------- K5: bn3 + bnds finalize, residual, relu, kl ---------------
__global__ __launch_bounds__(256) void final_kernel(
    float* __restrict__ out, const float* __restrict__ A,
    const float* __restrict__ g3, const float* __restrict__ b3,
    const float* __restrict__ gds, const float* __restrict__ bds,
    const double* __restrict__ dS)
{
  __shared__ float s3c[256], s3b[256], sdc[256], sdb[256];
  const int t = threadIdx.x;
  {
    double s  = dS[768 + t] * (1.0 / 3136.0);
    double vr = dS[1024 + t] * (1.0 / 3136.0) - s * s;
    float scale = g3[t] * rsqrtf((float)vr + 1e-5f);
    s3c[t] = scale; s3b[t] = b3[t] - (float)s * scale;
    s  = dS[t] * (1.0 / 3136.0);
    vr = dS[256 + t] * (1.0 / 3136.0) - s * s;
    scale = gds[t] * rsqrtf((float)vr + 1e-5f);
    sdc[t] = scale; sdb[t] = bds[t] - (float)s * scale;
  }
  __syncthreads();
  #pragma unroll
  for (int k = 0; k < 4; k++){
    int n = blockIdx.x * 1024 + k * 256 + t;
    int c = (n / HW) & 255;
    float h = out[n], aa = A[n];
    float r = fmaxf(aa * sdc[c] + sdb[c], 0.0f);
    out[n] = fmaxf(h * s3c[c] + s3b[c] + r, 0.0f);
  }
  if (blockIdx.x == 0 && t == 0){
    const int ns[4] = {32768, 8192, 36864, 16384};
    float kl = 0.0f;
    #pragma unroll
    for (int q = 0; q < 4; q++){
      double se  = dS[1280 + q * 4];
      double sel = dS[1280 + q * 4 + 1];
      double sef = dS[1280 + q * 4 + 2];
      double sq  = dS[1280 + q * 4 + 3];
      kl += (float)((((sel - sef) / se) - log(se) + log(sq)) / (double)ns[q]);
    }
    out[802816] = kl;
  }
}

// ===========================================================================
extern "C" void kernel_launch(void* const* d_in, const int* in_sizes, int n_in,
                              void* d_out, int out_size, void* d_ws, size_t ws_size,
                              hipStream_t stream)
{
  const float* x      = (const float*)d_in[0];
  const float* sw_ds  = (const float*)d_in[1];
  const float* sw_c1  = (const float*)d_in[2];
  const float* sw_c2  = (const float*)d_in[3];
  const float* sw_c3  = (const float*)d_in[4];
  const float* a_ds   = (const float*)d_in[5];
  const float* a_c1   = (const float*)d_in[6];
  const float* a_c2   = (const float*)d_in[7];
  const float* a_c3   = (const float*)d_in[8];
  const float* peg_w  = (const float*)d_in[9];
  const float* bn1_g  = (const float*)d_in[10];
  const float* bn1_b  = (const float*)d_in[11];
  const float* bn2_g  = (const float*)d_in[12];
  const float* bn2_b  = (const float*)d_in[13];
  const float* bn3_g  = (const float*)d_in[14];
  const float* bn3_b  = (const float*)d_in[15];
  const float* bnds_g = (const float*)d_in[16];
  const float* bnds_b = (const float*)d_in[17];
  const float* lap_ds = (const float*)d_in[18];
  const float* lap_c1 = (const float*)d_in[19];
  const float* lap_c2 = (const float*)d_in[20];
  const float* lap_c3 = (const float*)d_in[21];

  float* ws    = (float*)d_ws;
  float* f_c2  = ws;                        // 36864
  float* mmbuf = ws + 36864;                // 128
  double* dstat= (double*)(ws + 37120);     // 1344 doubles -> 2688 floats
  float* A     = ws + 39808;                // 802816
  float* T2    = ws + 842624;               // 200704
  float* T3    = ws + 1043328;              // 200704
  float* T2b   = ws + 1244032;              // 245760

  float* out = (float*)d_out;

  minmax_kernel<<<64, 256, 0, stream>>>(
      sw_ds, 32768, sw_c1, 8192, sw_c2, 36864, sw_c3, 16384, mmbuf, dstat);

  front_kernel<<<848, 256, 0, stream>>>(
      x, sw_ds, a_ds, lap_ds, sw_c1, a_c1, lap_c1,
      sw_c2, a_c2, lap_c2, f_c2, sw_c3, a_c3, lap_c3,
      peg_w, mmbuf, A, T2, dstat);

  bnapply_pad_kernel<<<256, 256, 0, stream>>>(T2, T2b, bn1_g, bn1_b, dstat);

  mid3x3_kernel<<<512, 256, 0, stream>>>(T2b, f_c2, T3, dstat);

  back_kernel<<<1024, 256, 0, stream>>>(T3, sw_c3, a_c3, mmbuf,
                                        bn2_g, bn2_b, out, dstat);

  final_kernel<<<784, 256, 0, stream>>>(out, A, bn3_g, bn3_b, bnds_g, bnds_b,
                                        dstat);
}